// Round 11
// baseline (343.770 us; speedup 1.0000x reference)
//
#include <hip/hip_runtime.h>
#include <hip/hip_bf16.h>
#include <stdint.h>
#include <math.h>

typedef unsigned short u16;
typedef __attribute__((ext_vector_type(8))) short frag8;   // 8 bf16 (4 VGPRs)
typedef __attribute__((ext_vector_type(4))) float f32x4;

#define Hdim 1024
#define Brows 4096

// out element offsets (fp32 elements)
#define OUT_B_OFF  8388608   // next_b base
#define OUT_D_OFF 16777216   // next_depth
#define OUT_F_OFF 16781312   // f
#define OUT_J_OFF 16785408   // j

// ---- workspace layout ----
// 0      .. 16K      : u (fp32 GEMV partial)        [memset 0]
// 16K    .. 24K      : wsum (2 x 1024 fp32: wa0+wc0, wa3+wc3)
// 24K    .. 40K      : kbuf (int per row)
// 40960  .. +16      : list counters (3 ints used)  [memset 0]
// 41024  .. +48K     : rowlists (3 x 4096 int, atomic-appended, cnt-bounded)
// 96K    ..          : bf16 region
#define WSUM_OFF  16384
#define KBUF_OFF  24576
#define CNT_OFF   40960
#define LISTS_OFF 41024
#define BF16_OFF  98304

// ---- bf16 workspace layout (u16-element offsets from ws+BF16_OFF) ----
#define XB      0u
#define B0B     4194304u
#define A1B     8388608u
#define B1B     12582912u
#define NA00B   16777216u
#define NA10B   20971520u
#define WA00B   25165824u   // 1024x3072
#define WA10B   28311552u   // 1024x2048
#define WB00B   30408704u   // 1024x3072
#define WB11B   33554432u   // 1024x2048
#define WB10B   35651584u   // 1024x2048
#define WS_BF_ELTS 37748736u
#define WS_NEED ((unsigned long long)BF16_OFF + (unsigned long long)WS_BF_ELTS * 2ull)

#define NO_BCOPY 0xFFFFFFFFu

__device__ __forceinline__ u16 f2bf(float f) {
    union { float f; unsigned int i; } v; v.f = f;
    unsigned int r = v.i + 0x7fffu + ((v.i >> 16) & 1u);   // RNE
    return (u16)(r >> 16);
}
__device__ __forceinline__ unsigned int pk2(float a, float b) {
    __hip_bfloat162 h = __float22bfloat162_rn(make_float2(a, b));
    union { __hip_bfloat162 h; unsigned int u; } v; v.h = h; return v.u;
}
__device__ __forceinline__ void gl_lds16(const u16* g, u16* l) {
    __builtin_amdgcn_global_load_lds(
        (const __attribute__((address_space(1))) unsigned int*)g,
        (__attribute__((address_space(3))) unsigned int*)l, 16, 0, 0);
}

// ================= fast path: gather-GEMM over compacted row lists =========
// (unchanged from r8 — XCD-locality swizzle verified +40%)
struct GDesc {
    unsigned int a0, a1s, a2;   // u16-elt offsets of A segments in ws16
    unsigned int w;             // weight offset (may point into a K-slice)
    unsigned int bcopy;         // u16-elt offset or NO_BCOPY
    int K;                      // K iteration extent (multiple of 64)
    int Kst;                    // W row stride in elements (>= K)
    const int* rows;            // row list (valid in [0,*pcnt))
    const int* pcnt;            // list length
    float* outp;
    const float* accp;          // null -> zero-init acc; else read partial
};
struct GPack { GDesc d[5]; };

__global__ __launch_bounds__(256)
void gemm_gather(u16* __restrict__ ws16, GPack gp)
{
    __shared__ alignas(16) u16 lsA[64 * 64];   // 8 KB
    __shared__ alignas(16) u16 lsB[64 * 64];   // 8 KB

    const GDesc g = gp.d[blockIdx.z];
    const int navail = *g.pcnt;

    // XCD-locality remap (bijective on the 64x16 plane)
    const int d  = blockIdx.y * 64 + blockIdx.x;
    const int s  = d >> 3;
    const int xp = ((s >> 4) << 3) | (d & 7);
    const int yp = s & 15;
    const int m0 = xp * 64;
    if (m0 >= navail) return;                   // empty tile (uniform)
    const int n0 = yp * 64;

    const int tid  = threadIdx.x;
    const int lane = tid & 63;
    const int wv   = tid >> 6;                  // wave -> n-subtile (16 cols)

    const int quad = lane >> 4;
    const int lcol = lane & 15;
    const int gcol = n0 + wv * 16 + lcol;

    int ridx[2];
#pragma unroll
    for (int i = 0; i < 2; ++i) {
        const int mi = m0 + (tid >> 3) + i * 32;
        ridx[i] = (mi < navail) ? g.rows[mi] : 0;
    }

    f32x4 acc[4];
#pragma unroll
    for (int i = 0; i < 4; ++i) acc[i] = (f32x4){0.f, 0.f, 0.f, 0.f};
    if (g.accp) {                               // continue earlier partial
#pragma unroll
        for (int i = 0; i < 4; ++i)
#pragma unroll
            for (int r = 0; r < 4; ++r) {
                const int mi = m0 + i * 16 + quad * 4 + r;
                if (mi < navail)
                    acc[i][r] = g.accp[(size_t)g.rows[mi] * 2048 + gcol];
            }
    }

    const u16* segp[3] = { ws16 + g.a0, ws16 + g.a1s, ws16 + g.a2 };
    const u16* W = ws16 + g.w;
    const int K = g.K;
    const int Kst = g.Kst;

    const int swz = ((tid & 7) ^ ((tid >> 3) & 7)) * 8;
    const int brow0 = tid >> 3;

    const int nkt = K / 64;
    for (int kt = 0; kt < nkt; ++kt) {
        const int seg = kt >> 4;
        const int kl  = (kt & 15) * 64;
        const u16* abase = segp[seg] + kl;
        const u16* wb = W + (size_t)n0 * Kst + kt * 64;
#pragma unroll
        for (int i = 0; i < 2; ++i)
            gl_lds16(abase + (size_t)ridx[i] * 1024 + swz, &lsA[(i * 256 + tid) * 8]);
#pragma unroll
        for (int i = 0; i < 2; ++i)
            gl_lds16(wb + (size_t)(i * 32 + brow0) * Kst + swz, &lsB[(i * 256 + tid) * 8]);
        __syncthreads();   // drains vmcnt -> LDS ready
#pragma unroll
        for (int ks = 0; ks < 2; ++ks) {
            const int kb = (ks * 32 + (lane >> 4) * 8) * 2;   // byte col offset
            frag8 af[4], bfr;
#pragma unroll
            for (int i = 0; i < 4; ++i) {
                const int ro = i * 16 + (lane & 15);
                af[i] = *(const frag8*)((const char*)lsA +
                            ((ro * 128 + kb) ^ ((ro & 7) << 4)));
            }
            {
                const int ro = wv * 16 + (lane & 15);
                bfr = *(const frag8*)((const char*)lsB +
                            ((ro * 128 + kb) ^ ((ro & 7) << 4)));
            }
#pragma unroll
            for (int i = 0; i < 4; ++i)
                acc[i] = __builtin_amdgcn_mfma_f32_16x16x32_bf16(af[i], bfr, acc[i], 0, 0, 0);
        }
        __syncthreads();   // readers done before next overwrite
    }

    // D layout: row = quad*4 + reg, col = lane&15 (m89-verified)
    u16* bc = (g.bcopy != NO_BCOPY) ? (ws16 + g.bcopy) : nullptr;
#pragma unroll
    for (int i = 0; i < 4; ++i) {
#pragma unroll
        for (int r = 0; r < 4; ++r) {
            const int mi = m0 + i * 16 + quad * 4 + r;
            if (mi >= navail) continue;         // list tail padding
            const int grow = g.rows[mi];
            const float v = acc[i][r];
            if (bc) bc[(size_t)grow * 1024 + gcol] = f2bf(v);
            g.outp[(size_t)grow * 2048 + gcol] = v;
        }
    }
}

// ---------- prep: u GEMV (blocks 0-511) + wsum precompute (block 512) ------
__global__ __launch_bounds__(256)
void prep(const float* __restrict__ w_b11, const float* __restrict__ w_att,
          float* __restrict__ u, float* __restrict__ wsum)
{
    const int bid = blockIdx.x;
    if (bid < 512) {
        const int k  = (bid & 7) * 256 + threadIdx.x;
        const int c0 = (bid >> 3) * 16;
        float s0 = 0.f, s3 = 0.f;
        for (int c = c0; c < c0 + 16; ++c) {
            const float w = w_b11[(size_t)c * 2048 + k];
            s0 += w * w_att[7168 + c];
            s3 += w * w_att[3 * 8192 + 7168 + c];
        }
        atomicAdd(&u[k], s0);
        atomicAdd(&u[2048 + k], s3);
        return;
    }
    const int c = threadIdx.x * 4;
    float4 a0 = *(const float4*)&w_att[2048 + c];
    float4 c0 = *(const float4*)&w_att[6144 + c];
    float4 a3 = *(const float4*)&w_att[3 * 8192 + 2048 + c];
    float4 c3 = *(const float4*)&w_att[3 * 8192 + 6144 + c];
    *(float4*)&wsum[c]        = make_float4(a0.x + c0.x, a0.y + c0.y, a0.z + c0.z, a0.w + c0.w);
    *(float4*)&wsum[1024 + c] = make_float4(a3.x + c3.x, a3.y + c3.y, a3.z + c3.z, a3.w + c3.w);
}

// ---------- decide_f: row decisions + streaming (convert + zero-fill) ------
// r10 post-mortem: interleave worked (+10us) but conversion blocks were 4KB
// each (scheduling churn, no ILP) and the 32MB zero-fill sat in the
// latency-bound ROW blocks.  r11 rebalance:
//   - streaming blocks: 2048 float4/block (8/thread, j-stride 256 keeps
//     loads AND stores lane-coalesced); element space = weights+b0 (4M f4)
//     + out row-0 zero-fill (2M f4) = 6M f4 = 3072 blocks.
//   - row blocks drop the zero-writes (dot product + k3-copy + X/a1/b1
//     bf16 conversion + scalars only).
//   - grid 4096 = 4*1024; group of 4 = 3 streaming + 1 row (mix from t=0).
// Zero numeric change: same values written by different blocks.
__global__ __launch_bounds__(256)
void decide_f(const float* __restrict__ X,
              const float* __restrict__ prev_a, const float* __restrict__ prev_b,
              const int* __restrict__ pdin,
              const float* __restrict__ w_att,
              const float* __restrict__ u,
              const float* __restrict__ wsum,
              int* __restrict__ kbuf,
              int* __restrict__ lists,
              int* __restrict__ cnt,
              u16* __restrict__ ws16,
              float* __restrict__ out,
              const float* __restrict__ wa00, const float* __restrict__ wa10,
              const float* __restrict__ wb00, const float* __restrict__ wb11,
              const float* __restrict__ wb10)
{
    const int grp = blockIdx.x >> 2;
    const int sub = blockIdx.x & 3;
    float* outA = out;
    float* outB = out + OUT_B_OFF;

    if (sub != 3) {
        // ---- streaming path: 8 float4 per thread, j-stride 256 ----
        const int cb = grp * 3 + sub;            // 0..3071
        const long long base = (long long)cb * 2048 + threadIdx.x;
        const float4 z4 = make_float4(0.f, 0.f, 0.f, 0.f);
#pragma unroll
        for (int j = 0; j < 8; ++j) {
            const long long e = base + j * 256;
            if (e < 4194304) {                   // fp32 -> bf16 conversion
                const float* src;
                unsigned int dst;
                long long idx;
                if (e < 786432) {                        // wa00 (1024x3072)
                    idx = e;             src = wa00 + idx * 4; dst = WA00B;
                } else if (e < 1310720) {                // wa10 (1024x2048)
                    idx = e - 786432;    src = wa10 + idx * 4; dst = WA10B;
                } else if (e < 2097152) {                // wb00
                    idx = e - 1310720;   src = wb00 + idx * 4; dst = WB00B;
                } else if (e < 2621440) {                // wb11
                    idx = e - 2097152;   src = wb11 + idx * 4; dst = WB11B;
                } else if (e < 3145728) {                // wb10
                    idx = e - 2621440;   src = wb10 + idx * 4; dst = WB10B;
                } else {                                 // b0 (stride 2048)
                    idx = e - 3145728;
                    src = prev_b + (idx >> 8) * 2048 + (idx & 255) * 4;  dst = B0B;
                }
                float4 v = *(const float4*)src;
                uint2 h = { pk2(v.x, v.y), pk2(v.z, v.w) };
                *(uint2*)&ws16[(size_t)dst + idx * 4] = h;
            } else {                             // out row-0 zero-fill
                const long long z = e - 4194304;         // < 2097152
                if (z < 1048576)
                    *(float4*)&outA[(z >> 8) * 2048 + (z & 255) * 4] = z4;
                else {
                    const long long z2 = z - 1048576;
                    *(float4*)&outB[(z2 >> 8) * 2048 + (z2 & 255) * 4] = z4;
                }
            }
        }
        return;
    }

    const int lane = threadIdx.x & 63;
    const int wv   = threadIdx.x >> 6;
    const int b    = grp * 4 + wv;
    const int pd   = pdin[b];

    const float* a1 = prev_a + (size_t)b * 2048 + 1024;
    const float* b1 = prev_b + (size_t)b * 2048 + 1024;
    const float* xr = X + (size_t)b * 1024;

    int k;
    float fv;
    if (pd == 0) {
        k = 2; fv = 1.f;
    } else {
        float d0 = 0.f, d3 = 0.f;
        const float* w0 = w_att;
        const float* w3 = w_att + 3 * 8192;
        const float* u0 = u;
        const float* u3 = u + 2048;
#pragma unroll
        for (int uu = 0; uu < 2; ++uu) {
            const int c = lane * 16 + uu * 8;
#pragma unroll
            for (int q = 0; q < 2; ++q) {
                const int cc = c + q * 4;
                float4 av  = *(const float4*)&a1[cc];
                float4 bv  = *(const float4*)&b1[cc];
                float4 xv  = *(const float4*)&xr[cc];
                float4 ws0 = *(const float4*)&wsum[cc];          // = wa0+wc0
                float4 ws3 = *(const float4*)&wsum[1024 + cc];   // = wa3+wc3
                float4 wb0 = *(const float4*)&w0[3072 + cc];
                float4 wb3 = *(const float4*)&w3[3072 + cc];
                float4 ux0 = *(const float4*)&u0[cc];
                float4 ux3 = *(const float4*)&u3[cc];
                float4 ub0 = *(const float4*)&u0[1024 + cc];
                float4 ub3 = *(const float4*)&u3[1024 + cc];
                d0 += av.x*ws0.x + av.y*ws0.y + av.z*ws0.z + av.w*ws0.w;
                d3 += av.x*ws3.x + av.y*ws3.y + av.z*ws3.z + av.w*ws3.w;
                d0 += bv.x*wb0.x + bv.y*wb0.y + bv.z*wb0.z + bv.w*wb0.w;
                d3 += bv.x*wb3.x + bv.y*wb3.y + bv.z*wb3.z + bv.w*wb3.w;
                d0 += xv.x*ux0.x + xv.y*ux0.y + xv.z*ux0.z + xv.w*ux0.w;
                d3 += xv.x*ux3.x + xv.y*ux3.y + xv.z*ux3.z + xv.w*ux3.w;
                d0 += bv.x*ub0.x + bv.y*ub0.y + bv.z*ub0.z + bv.w*ub0.w;
                d3 += bv.x*ub3.x + bv.y*ub3.y + bv.z*ub3.z + bv.w*ub3.w;
            }
        }
#pragma unroll
        for (int off = 32; off; off >>= 1) {
            d0 += __shfl_xor(d0, off, 64);
            d3 += __shfl_xor(d3, off, 64);
        }
        k = (d3 > d0) ? 3 : 0;
        fv = (k == 3) ? 1.f : 0.f;
    }
    const float jv = (pd == 0) ? 0.f : fv;
    const int nd = (k == 2) ? pd + 1 : pd;

    if (k == 3) {
#pragma unroll
        for (int uu = 0; uu < 4; ++uu) {
            const int c = uu * 256 + lane * 4;
            *(float4*)&outA[(size_t)b * 2048 + 1024 + c] = *(const float4*)&a1[c];
        }
    }
    {
        // fused bf16 conversion of X/a1/b1 rows (sources L1/L2-hot;
        // bit-identical to the old convert_all output)
#pragma unroll
        for (int uu = 0; uu < 4; ++uu) {
            const int c = uu * 256 + lane * 4;
            float4 xv = *(const float4*)&xr[c];
            float4 av = *(const float4*)&a1[c];
            float4 bv = *(const float4*)&b1[c];
            uint2 hx = { pk2(xv.x, xv.y), pk2(xv.z, xv.w) };
            uint2 ha = { pk2(av.x, av.y), pk2(av.z, av.w) };
            uint2 hb = { pk2(bv.x, bv.y), pk2(bv.z, bv.w) };
            *(uint2*)&ws16[XB  + (size_t)b * 1024 + c] = hx;
            *(uint2*)&ws16[A1B + (size_t)b * 1024 + c] = ha;
            *(uint2*)&ws16[B1B + (size_t)b * 1024 + c] = hb;
        }
    }
    if (lane == 0) {
        kbuf[b] = k;
        const int j = (k == 0) ? 0 : (k == 2) ? 1 : 2;
        const int pos = atomicAdd(&cnt[j], 1);
        lists[j * 4096 + pos] = b;
        out[OUT_D_OFF + b] = (float)nd;
        out[OUT_F_OFF + b] = fv;
        out[OUT_J_OFF + b] = jv;
    }
}

// ================= fallback path (proven round-6 GEMM) =================
#define BMf 128
#define BNf 64
#define LDK 72

struct RegTile { float4 a[8]; float4 b[4]; };

__device__ __forceinline__ void load_tile(RegTile& s,
        const float* const* segp, const int* segs,
        const float* __restrict__ W, int K, int kn,
        int m0, int n0, int lr, int lc)
{
    const int seg = kn >> 4;
    const int kl  = (kn & 15) * 64;
    const float* ab = segp[seg];
    const int astr  = segs[seg];
#pragma unroll
    for (int i = 0; i < 8; ++i)
        s.a[i] = *(const float4*)(ab + (size_t)(m0 + i * 16 + lr) * astr + kl + lc);
#pragma unroll
    for (int i = 0; i < 4; ++i)
        s.b[i] = *(const float4*)(W + (size_t)(n0 + i * 16 + lr) * K + kn * 64 + lc);
}
__device__ __forceinline__ void stage_tile(const RegTile& s, u16* LA, u16* LB,
                                           int lr, int lc)
{
#pragma unroll
    for (int i = 0; i < 8; ++i) {
        uint2 h = { pk2(s.a[i].x, s.a[i].y), pk2(s.a[i].z, s.a[i].w) };
        *(uint2*)&LA[(i * 16 + lr) * LDK + lc] = h;
    }
#pragma unroll
    for (int i = 0; i < 4; ++i) {
        uint2 h = { pk2(s.b[i].x, s.b[i].y), pk2(s.b[i].z, s.b[i].w) };
        *(uint2*)&LB[(i * 16 + lr) * LDK + lc] = h;
    }
}
__device__ __forceinline__ void do_mfma_f(const u16* LA, const u16* LB,
                                          int wm, int wn, int lane, f32x4 acc[4][2])
{
#pragma unroll
    for (int ks = 0; ks < 2; ++ks) {
        const int kc = ks * 32 + (lane >> 4) * 8;
        frag8 af[4], bf[2];
#pragma unroll
        for (int i = 0; i < 4; ++i)
            af[i] = *(const frag8*)&LA[(wm * 64 + i * 16 + (lane & 15)) * LDK + kc];
#pragma unroll
        for (int j = 0; j < 2; ++j)
            bf[j] = *(const frag8*)&LB[(wn * 32 + j * 16 + (lane & 15)) * LDK + kc];
#pragma unroll
        for (int i = 0; i < 4; ++i)
#pragma unroll
            for (int j = 0; j < 2; ++j)
                acc[i][j] = __builtin_amdgcn_mfma_f32_16x16x32_bf16(af[i], bf[j], acc[i][j], 0, 0, 0);
    }
}

__global__ __launch_bounds__(256)
void gemm_k(const float* __restrict__ a0, int as0,
            const float* __restrict__ a1p, int as1,
            const float* __restrict__ a2p, int as2,
            const float* __restrict__ W, int K,
            const int* __restrict__ gate, int ksel,
            float* __restrict__ outp, int ostr)
{
    __shared__ alignas(16) u16 lsA[2][BMf * LDK];
    __shared__ alignas(16) u16 lsB[2][BNf * LDK];

    const int tid  = threadIdx.x;
    const int lane = tid & 63;
    const int wv   = tid >> 6;
    const int wm   = wv >> 1, wn = wv & 1;
    const int m0   = blockIdx.x * BMf;
    const int n0   = blockIdx.y * BNf;
    const int lr = tid >> 4;
    const int lc = (tid & 15) * 4;

    f32x4 acc[4][2];
#pragma unroll
    for (int i = 0; i < 4; ++i)
#pragma unroll
        for (int j = 0; j < 2; ++j) acc[i][j] = (f32x4){0.f, 0.f, 0.f, 0.f};

    const float* segp[3] = { a0, a1p, a2p };
    const int    segs[3] = { as0, as1, as2 };

    const int nkt = K / 64;
    RegTile S0, S1;
    load_tile(S0, segp, segs, W, K, 0, m0, n0, lr, lc);
    load_tile(S1, segp, segs, W, K, 1, m0, n0, lr, lc);
    stage_tile(S0, lsA[0], lsB[0], lr, lc);
    __syncthreads();

    for (int kt = 0; kt < nkt; kt += 2) {
        if (kt + 2 < nkt) load_tile(S0, segp, segs, W, K, kt + 2, m0, n0, lr, lc);
        do_mfma_f(lsA[0], lsB[0], wm, wn, lane, acc);
        stage_tile(S1, lsA[1], lsB[1], lr, lc);
        __syncthreads();
        if (kt + 3 < nkt) load_tile(S1, segp, segs, W, K, kt + 3, m0, n0, lr, lc);
        do_mfma_f(lsA[1], lsB[1], wm, wn, lane, acc);
        if (kt + 2 < nkt) {
            stage_tile(S0, lsA[0], lsB[0], lr, lc);
            __syncthreads();
        }
    }

    const int quad = lane >> 4;
    const int lcol = lane & 15;
#pragma unroll
    for (int i = 0; i < 4; ++i) {
#pragma unroll
        for (int r = 0; r < 4; ++r) {
            const int grow = m0 + wm * 64 + i * 16 + quad * 4 + r;
            if (gate[grow] == ksel) {
#pragma unroll
                for (int j = 0; j < 2; ++j) {
                    const int gcol = n0 + wn * 32 + j * 16 + lcol;
                    outp[(size_t)grow * ostr + gcol] = acc[i][j][r];
                }
            }
        }
    }
}

// ---------- prep_u + decide (fallback path only) ----------
__global__ __launch_bounds__(256)
void prep_u(const float* __restrict__ w_b11, const float* __restrict__ w_att,
            float* __restrict__ u)
{
    const int k  = (blockIdx.x & 7) * 256 + threadIdx.x;
    const int c0 = (blockIdx.x >> 3) * 16;
    float s0 = 0.f, s3 = 0.f;
    for (int c = c0; c < c0 + 16; ++c) {
        const float w = w_b11[(size_t)c * 2048 + k];
        s0 += w * w_att[7168 + c];
        s3 += w * w_att[3 * 8192 + 7168 + c];
    }
    atomicAdd(&u[k], s0);
    atomicAdd(&u[2048 + k], s3);
}

__global__ __launch_bounds__(256)
void decide(const float* __restrict__ X,
            const float* __restrict__ prev_a, const float* __restrict__ prev_b,
            const int* __restrict__ pdin,
            const float* __restrict__ w_att,
            const float* __restrict__ u,
            int* __restrict__ kbuf,
            float* __restrict__ out)
{
    const int lane = threadIdx.x & 63;
    const int wv   = threadIdx.x >> 6;
    const int b    = blockIdx.x * 4 + wv;
    const int pd   = pdin[b];

    const float* a1 = prev_a + (size_t)b * 2048 + 1024;
    const float* b1 = prev_b + (size_t)b * 2048 + 1024;
    const float* xr = X + (size_t)b * 1024;

    int k;
    float fv;
    if (pd == 0) {
        k = 2; fv = 1.f;
    } else {
        float d0 = 0.f, d3 = 0.f;
        const float* w0 = w_att;
        const float* w3 = w_att + 3 * 8192;
        const float* u0 = u;
        const float* u3 = u + 2048;
#pragma unroll
        for (int uu = 0; uu < 2; ++uu) {
            const int c = lane * 16 + uu * 8;
#pragma unroll
            for (int q = 0; q < 2; ++q) {
                const int cc = c + q * 4;
                float4 av = *(const float4*)&a1[cc];
                float4 bv = *(const float4*)&b1[cc];
                float4 xv = *(const float4*)&xr[cc];
                float4 wa0 = *(const float4*)&w0[2048 + cc];
                float4 wb0 = *(const float4*)&w0[3072 + cc];
                float4 wc0 = *(const float4*)&w0[6144 + cc];
                float4 wa3 = *(const float4*)&w3[2048 + cc];
                float4 wb3 = *(const float4*)&w3[3072 + cc];
                float4 wc3 = *(const float4*)&w3[6144 + cc];
                float4 ux0 = *(const float4*)&u0[cc];
                float4 ux3 = *(const float4*)&u3[cc];
                float4 ub0 = *(const float4*)&u0[1024 + cc];
                float4 ub3 = *(const float4*)&u3[1024 + cc];
                d0 += av.x*(wa0.x+wc0.x) + av.y*(wa0.y+wc0.y) + av.z*(wa0.z+wc0.z) + av.w*(wa0.w+wc0.w);
                d3 += av.x*(wa3.x+wc3.x) + av.y*(wa3.y+wc3.y) + av.z*(wa3.z+wc3.z) + av.w*(wa3.w+wc3.w);
                d0 += bv.x*wb0.x + bv.y*wb0.y + bv.z*wb0.z + bv.w*wb0.w;
                d3 += bv.x*wb3.x + bv.y*wb3.y + bv.z*wb3.z + bv.w*wb3.w;
                d0 += xv.x*ux0.x + xv.y*ux0.y + xv.z*ux0.z + xv.w*ux0.w;
                d3 += xv.x*ux3.x + xv.y*ux3.y + xv.z*ux3.z + xv.w*ux3.w;
                d0 += bv.x*ub0.x + bv.y*ub0.y + bv.z*ub0.z + bv.w*ub0.w;
                d3 += bv.x*ub3.x + bv.y*ub3.y + bv.z*ub3.z + bv.w*ub3.w;
            }
        }
#pragma unroll
        for (int off = 32; off; off >>= 1) {
            d0 += __shfl_xor(d0, off, 64);
            d3 += __shfl_xor(d3, off, 64);
        }
        k = (d3 > d0) ? 3 : 0;
        fv = (k == 3) ? 1.f : 0.f;
    }
    const float jv = (pd == 0) ? 0.f : fv;
    const int nd = (k == 2) ? pd + 1 : pd;

    float* outA = out;
    float* outB = out + OUT_B_OFF;

    const float4 z4 = make_float4(0.f, 0.f, 0.f, 0.f);
#pragma unroll
    for (int uu = 0; uu < 4; ++uu) {
        const int c = uu * 256 + lane * 4;
        *(float4*)&outA[(size_t)b * 2048 + c] = z4;
        *(float4*)&outB[(size_t)b * 2048 + c] = z4;
    }
    if (k == 3) {
#pragma unroll
        for (int uu = 0; uu < 4; ++uu) {
            const int c = uu * 256 + lane * 4;
            *(float4*)&outA[(size_t)b * 2048 + 1024 + c] = *(const float4*)&a1[c];
        }
    }
    if (lane == 0) {
        kbuf[b] = k;
        out[OUT_D_OFF + b] = (float)nd;
        out[OUT_F_OFF + b] = fv;
        out[OUT_J_OFF + b] = jv;
    }
}

// ---------- launch ----------
extern "C" void kernel_launch(void* const* d_in, const int* in_sizes, int n_in,
                              void* d_out, int out_size, void* d_ws, size_t ws_size,
                              hipStream_t stream)
{
    const float* X      = (const float*)d_in[0];
    const float* prev_a = (const float*)d_in[3];
    const float* prev_b = (const float*)d_in[4];
    const int*   pd     = (const int*)d_in[5];
    const float* w_a00  = (const float*)d_in[6];
    const float* w_a10  = (const float*)d_in[7];
    const float* w_b00  = (const float*)d_in[8];
    const float* w_b11  = (const float*)d_in[9];
    const float* w_b10  = (const float*)d_in[10];
    const float* w_att  = (const float*)d_in[12];

    float* u     = (float*)d_ws;                        // 16 KB
    float* wsum  = (float*)((char*)d_ws + WSUM_OFF);    // 8 KB
    int*   kbuf  = (int*)((char*)d_ws + KBUF_OFF);      // 16 KB
    int*   cnt   = (int*)((char*)d_ws + CNT_OFF);       // 16 B
    int*   lists = (int*)((char*)d_ws + LISTS_OFF);     // 48 KB
    u16*   ws16  = (u16*)((char*)d_ws + BF16_OFF);

    const float* a1 = prev_a + 1024;
    const float* b0 = prev_b;
    const float* b1 = prev_b + 1024;

    float* out   = (float*)d_out;
    float* outA1 = out + 1024;
    float* outB1 = out + OUT_B_OFF + 1024;

    dim3 blk(256);
    const bool fast = (ws_size >= WS_NEED);

    if (fast) {
        // memset covers u [0,16K) + cnt [40960,+16) (wsum/kbuf overwritten
        // before any read; lists bounded by cnt)
        hipMemsetAsync(d_ws, 0, CNT_OFF + 64, stream);
        prep<<<dim3(513), blk, 0, stream>>>(w_b11, w_att, u, wsum);
        decide_f<<<dim3(4096), blk, 0, stream>>>(X, prev_a, prev_b, pd,
            w_att, u, wsum, kbuf, lists, cnt, ws16, out,
            w_a00, w_a10, w_b00, w_b11, w_b10);

        int* l0 = lists;            // k==0 rows
        int* l2 = lists + 4096;     // k==2 rows
        int* l3 = lists + 8192;     // k==3 rows

        // Launch A (5 z): G1 (na00, k0), G2 (na10, k2),
        //   G4a (nb00 prefix [X,a1] -> fp32 partial in outB1),
        //   G3 (nb11, k3), G5a (nb10 prefix [X] -> partial in outB1).
        GPack p1;
        p1.d[0] = { XB, B0B, A1B, WA00B, NA00B,    3072, 3072, l0, &cnt[0], outA1, nullptr };
        p1.d[1] = { XB, B0B, 0u,  WA10B, NA10B,    2048, 2048, l2, &cnt[1], outA1, nullptr };
        p1.d[2] = { XB, A1B, 0u,  WB00B, NO_BCOPY, 2048, 3072, l0, &cnt[0], outB1, nullptr };
        p1.d[3] = { XB, B1B, 0u,  WB11B, NO_BCOPY, 2048, 2048, l3, &cnt[2], outB1, nullptr };
        p1.d[4] = { XB, 0u,  0u,  WB10B, NO_BCOPY, 1024, 2048, l2, &cnt[1], outB1, nullptr };
        gemm_gather<<<dim3(64, 16, 5), blk, 0, stream>>>(ws16, p1);

        // Launch B (2 z): G4b (nb00 suffix over na00, acc-init from partial),
        //   G5b (nb10 suffix over na10).  Exact fp32 accum order preserved.
        GPack p2;
        p2.d[0] = { NA00B, 0u, 0u, WB00B + 2048u, NO_BCOPY, 1024, 3072, l0, &cnt[0], outB1, outB1 };
        p2.d[1] = { NA10B, 0u, 0u, WB10B + 1024u, NO_BCOPY, 1024, 2048, l2, &cnt[1], outB1, outB1 };
        p2.d[2] = p2.d[0];   // unused (gridDim.z == 2)
        p2.d[3] = p2.d[0];
        p2.d[4] = p2.d[0];
        gemm_gather<<<dim3(64, 16, 2), blk, 0, stream>>>(ws16, p2);
    } else {
        // ---- fallback: proven round-6 fp32-staging path ----
        hipMemsetAsync(u, 0, 16384, stream);
        prep_u<<<dim3(512), blk, 0, stream>>>(w_b11, w_att, u);
        decide<<<dim3(Brows / 4), blk, 0, stream>>>(X, prev_a, prev_b, pd, w_att, u,
                                                    kbuf, out);
        dim3 grid(Brows / BMf, Hdim / BNf);
        gemm_k<<<grid, blk, 0, stream>>>(X, 1024, b0, 2048, a1, 2048,
                                         w_a00, 3072, kbuf, 0, outA1, 2048);
        gemm_k<<<grid, blk, 0, stream>>>(X, 1024, b0, 2048, nullptr, 0,
                                         w_a10, 2048, kbuf, 2, outA1, 2048);
        gemm_k<<<grid, blk, 0, stream>>>(X, 1024, b1, 2048, nullptr, 0,
                                         w_b11, 2048, pd, 1, outB1, 2048);
        gemm_k<<<grid, blk, 0, stream>>>(X, 1024, a1, 2048, outA1, 2048,
                                         w_b00, 3072, kbuf, 0, outB1, 2048);
        gemm_k<<<grid, blk, 0, stream>>>(X, 1024, outA1, 2048, nullptr, 0,
                                         w_b10, 2048, kbuf, 2, outB1, 2048);
    }
}

// Round 12
// 342.638 us; speedup vs baseline: 1.0033x; 1.0033x over previous
//
#include <hip/hip_runtime.h>
#include <hip/hip_bf16.h>
#include <stdint.h>
#include <math.h>

typedef unsigned short u16;
typedef __attribute__((ext_vector_type(8))) short frag8;   // 8 bf16 (4 VGPRs)
typedef __attribute__((ext_vector_type(4))) float f32x4;

#define Hdim 1024
#define Brows 4096

// out element offsets (fp32 elements)
#define OUT_B_OFF  8388608   // next_b base
#define OUT_D_OFF 16777216   // next_depth
#define OUT_F_OFF 16781312   // f
#define OUT_J_OFF 16785408   // j

// ---- workspace layout ----
// 0      .. 16K      : u (fp32 GEMV partial)        [memset 0]
// 16K    .. 24K      : wsum (2 x 1024 fp32: wa0+wc0, wa3+wc3)
// 24K    .. 40K      : kbuf (int per row)
// 40960  .. +16      : list counters (3 ints used)  [memset 0]
// 41024  .. +48K     : rowlists (3 x 4096 int, atomic-appended, cnt-bounded)
// 96K    ..          : bf16 region
#define WSUM_OFF  16384
#define KBUF_OFF  24576
#define CNT_OFF   40960
#define LISTS_OFF 41024
#define BF16_OFF  98304

// ---- bf16 workspace layout (u16-element offsets from ws+BF16_OFF) ----
#define XB      0u
#define B0B     4194304u
#define A1B     8388608u
#define B1B     12582912u
#define NA00B   16777216u
#define NA10B   20971520u
#define WA00B   25165824u   // 1024x3072
#define WA10B   28311552u   // 1024x2048
#define WB00B   30408704u   // 1024x3072
#define WB11B   33554432u   // 1024x2048
#define WB10B   35651584u   // 1024x2048
#define WS_BF_ELTS 37748736u
#define WS_NEED ((unsigned long long)BF16_OFF + (unsigned long long)WS_BF_ELTS * 2ull)

#define NO_BCOPY 0xFFFFFFFFu

__device__ __forceinline__ u16 f2bf(float f) {
    union { float f; unsigned int i; } v; v.f = f;
    unsigned int r = v.i + 0x7fffu + ((v.i >> 16) & 1u);   // RNE
    return (u16)(r >> 16);
}
__device__ __forceinline__ unsigned int pk2(float a, float b) {
    __hip_bfloat162 h = __float22bfloat162_rn(make_float2(a, b));
    union { __hip_bfloat162 h; unsigned int u; } v; v.h = h; return v.u;
}
__device__ __forceinline__ void gl_lds16(const u16* g, u16* l) {
    __builtin_amdgcn_global_load_lds(
        (const __attribute__((address_space(1))) unsigned int*)g,
        (__attribute__((address_space(3))) unsigned int*)l, 16, 0, 0);
}

// ================= fast path: gather-GEMM over compacted row lists =========
// (unchanged from r8 — XCD-locality swizzle verified +40%)
struct GDesc {
    unsigned int a0, a1s, a2;   // u16-elt offsets of A segments in ws16
    unsigned int w;             // weight offset (may point into a K-slice)
    unsigned int bcopy;         // u16-elt offset or NO_BCOPY
    int K;                      // K iteration extent (multiple of 64)
    int Kst;                    // W row stride in elements (>= K)
    const int* rows;            // row list (valid in [0,*pcnt))
    const int* pcnt;            // list length
    float* outp;
    const float* accp;          // null -> zero-init acc; else read partial
};
struct GPack { GDesc d[5]; };

__global__ __launch_bounds__(256)
void gemm_gather(u16* __restrict__ ws16, GPack gp)
{
    __shared__ alignas(16) u16 lsA[64 * 64];   // 8 KB
    __shared__ alignas(16) u16 lsB[64 * 64];   // 8 KB

    const GDesc g = gp.d[blockIdx.z];
    const int navail = *g.pcnt;

    // XCD-locality remap (bijective on the 64x16 plane)
    const int d  = blockIdx.y * 64 + blockIdx.x;
    const int s  = d >> 3;
    const int xp = ((s >> 4) << 3) | (d & 7);
    const int yp = s & 15;
    const int m0 = xp * 64;
    if (m0 >= navail) return;                   // empty tile (uniform)
    const int n0 = yp * 64;

    const int tid  = threadIdx.x;
    const int lane = tid & 63;
    const int wv   = tid >> 6;                  // wave -> n-subtile (16 cols)

    const int quad = lane >> 4;
    const int lcol = lane & 15;
    const int gcol = n0 + wv * 16 + lcol;

    int ridx[2];
#pragma unroll
    for (int i = 0; i < 2; ++i) {
        const int mi = m0 + (tid >> 3) + i * 32;
        ridx[i] = (mi < navail) ? g.rows[mi] : 0;
    }

    f32x4 acc[4];
#pragma unroll
    for (int i = 0; i < 4; ++i) acc[i] = (f32x4){0.f, 0.f, 0.f, 0.f};
    if (g.accp) {                               // continue earlier partial
#pragma unroll
        for (int i = 0; i < 4; ++i)
#pragma unroll
            for (int r = 0; r < 4; ++r) {
                const int mi = m0 + i * 16 + quad * 4 + r;
                if (mi < navail)
                    acc[i][r] = g.accp[(size_t)g.rows[mi] * 2048 + gcol];
            }
    }

    const u16* segp[3] = { ws16 + g.a0, ws16 + g.a1s, ws16 + g.a2 };
    const u16* W = ws16 + g.w;
    const int K = g.K;
    const int Kst = g.Kst;

    const int swz = ((tid & 7) ^ ((tid >> 3) & 7)) * 8;
    const int brow0 = tid >> 3;

    const int nkt = K / 64;
    for (int kt = 0; kt < nkt; ++kt) {
        const int seg = kt >> 4;
        const int kl  = (kt & 15) * 64;
        const u16* abase = segp[seg] + kl;
        const u16* wb = W + (size_t)n0 * Kst + kt * 64;
#pragma unroll
        for (int i = 0; i < 2; ++i)
            gl_lds16(abase + (size_t)ridx[i] * 1024 + swz, &lsA[(i * 256 + tid) * 8]);
#pragma unroll
        for (int i = 0; i < 2; ++i)
            gl_lds16(wb + (size_t)(i * 32 + brow0) * Kst + swz, &lsB[(i * 256 + tid) * 8]);
        __syncthreads();   // drains vmcnt -> LDS ready
#pragma unroll
        for (int ks = 0; ks < 2; ++ks) {
            const int kb = (ks * 32 + (lane >> 4) * 8) * 2;   // byte col offset
            frag8 af[4], bfr;
#pragma unroll
            for (int i = 0; i < 4; ++i) {
                const int ro = i * 16 + (lane & 15);
                af[i] = *(const frag8*)((const char*)lsA +
                            ((ro * 128 + kb) ^ ((ro & 7) << 4)));
            }
            {
                const int ro = wv * 16 + (lane & 15);
                bfr = *(const frag8*)((const char*)lsB +
                            ((ro * 128 + kb) ^ ((ro & 7) << 4)));
            }
#pragma unroll
            for (int i = 0; i < 4; ++i)
                acc[i] = __builtin_amdgcn_mfma_f32_16x16x32_bf16(af[i], bfr, acc[i], 0, 0, 0);
        }
        __syncthreads();   // readers done before next overwrite
    }

    // D layout: row = quad*4 + reg, col = lane&15 (m89-verified)
    u16* bc = (g.bcopy != NO_BCOPY) ? (ws16 + g.bcopy) : nullptr;
#pragma unroll
    for (int i = 0; i < 4; ++i) {
#pragma unroll
        for (int r = 0; r < 4; ++r) {
            const int mi = m0 + i * 16 + quad * 4 + r;
            if (mi >= navail) continue;         // list tail padding
            const int grow = g.rows[mi];
            const float v = acc[i][r];
            if (bc) bc[(size_t)grow * 1024 + gcol] = f2bf(v);
            g.outp[(size_t)grow * 2048 + gcol] = v;
        }
    }
}

// ---------- prep: u GEMV (blocks 0-511) + wsum precompute (block 512) ------
__global__ __launch_bounds__(256)
void prep(const float* __restrict__ w_b11, const float* __restrict__ w_att,
          float* __restrict__ u, float* __restrict__ wsum)
{
    const int bid = blockIdx.x;
    if (bid < 512) {
        const int k  = (bid & 7) * 256 + threadIdx.x;
        const int c0 = (bid >> 3) * 16;
        float s0 = 0.f, s3 = 0.f;
        for (int c = c0; c < c0 + 16; ++c) {
            const float w = w_b11[(size_t)c * 2048 + k];
            s0 += w * w_att[7168 + c];
            s3 += w * w_att[3 * 8192 + 7168 + c];
        }
        atomicAdd(&u[k], s0);
        atomicAdd(&u[2048 + k], s3);
        return;
    }
    const int c = threadIdx.x * 4;
    float4 a0 = *(const float4*)&w_att[2048 + c];
    float4 c0 = *(const float4*)&w_att[6144 + c];
    float4 a3 = *(const float4*)&w_att[3 * 8192 + 2048 + c];
    float4 c3 = *(const float4*)&w_att[3 * 8192 + 6144 + c];
    *(float4*)&wsum[c]        = make_float4(a0.x + c0.x, a0.y + c0.y, a0.z + c0.z, a0.w + c0.w);
    *(float4*)&wsum[1024 + c] = make_float4(a3.x + c3.x, a3.y + c3.y, a3.z + c3.z, a3.w + c3.w);
}

// ---------- decide_f: row decisions + streaming (convert + zero-fill) ------
// r11 post-mortem: per-element runtime branches inside the unrolled
// streaming loop serialized 8 HBM round-trips/thread while block count
// dropped 5x -> 114us.  KEY FACT: all region boundaries (in float4 units)
// are multiples of 2048, so each streaming block's 2048-elt range lies in
// EXACTLY ONE region.  r12: hoist the region select to block level
// (uniform/scalar), then issue all 8 loads branch-free into registers
// (8 outstanding loads/thread), then 8 convert+stores.  Zero-fill blocks
// are 8 plain stores.  Same bytes, same values — bit-identical.
// Grid 4096 = 1024 groups x {3 streaming + 1 row} (mix from t=0).
__global__ __launch_bounds__(256)
void decide_f(const float* __restrict__ X,
              const float* __restrict__ prev_a, const float* __restrict__ prev_b,
              const int* __restrict__ pdin,
              const float* __restrict__ w_att,
              const float* __restrict__ u,
              const float* __restrict__ wsum,
              int* __restrict__ kbuf,
              int* __restrict__ lists,
              int* __restrict__ cnt,
              u16* __restrict__ ws16,
              float* __restrict__ out,
              const float* __restrict__ wa00, const float* __restrict__ wa10,
              const float* __restrict__ wb00, const float* __restrict__ wb11,
              const float* __restrict__ wb10)
{
    const int grp = blockIdx.x >> 2;
    const int sub = blockIdx.x & 3;
    float* outA = out;
    float* outB = out + OUT_B_OFF;

    if (sub != 3) {
        // ---- streaming path: block-uniform region, 8 f4/thread ----
        const int cb = grp * 3 + sub;            // 0..3071
        const long long e0 = (long long)cb * 2048;
        const int tid = threadIdx.x;

        if (e0 >= 4194304) {                     // out row-0 zero-fill
            const long long z0 = e0 - 4194304;
            float* dstp = (z0 < 1048576) ? outA : outB;
            const long long zb = (z0 < 1048576) ? z0 : z0 - 1048576;
            const float4 z4 = make_float4(0.f, 0.f, 0.f, 0.f);
#pragma unroll
            for (int j = 0; j < 8; ++j) {
                const long long z = zb + tid + j * 256;
                *(float4*)&dstp[(z >> 8) * 2048 + (z & 255) * 4] = z4;
            }
            return;
        }

        // fp32 -> bf16 conversion; region uniform across the block
        const float* src; unsigned int dst; long long rb; bool strided;
        if (e0 < 786432)       { src = wa00;   dst = WA00B; rb = 0;       strided = false; }
        else if (e0 < 1310720) { src = wa10;   dst = WA10B; rb = 786432;  strided = false; }
        else if (e0 < 2097152) { src = wb00;   dst = WB00B; rb = 1310720; strided = false; }
        else if (e0 < 2621440) { src = wb11;   dst = WB11B; rb = 2097152; strided = false; }
        else if (e0 < 3145728) { src = wb10;   dst = WB10B; rb = 2621440; strided = false; }
        else                   { src = prev_b; dst = B0B;   rb = 3145728; strided = true;  }

        const long long i0 = e0 - rb + tid;
        float4 v[8];
        if (strided) {                           // b0: row stride 2048 fp32
#pragma unroll
            for (int j = 0; j < 8; ++j) {
                const long long idx = i0 + j * 256;
                v[j] = *(const float4*)(src + (idx >> 8) * 2048 + (idx & 255) * 4);
            }
        } else {                                 // contiguous weight
#pragma unroll
            for (int j = 0; j < 8; ++j) {
                const long long idx = i0 + j * 256;
                v[j] = *(const float4*)(src + idx * 4);
            }
        }
#pragma unroll
        for (int j = 0; j < 8; ++j) {
            const long long idx = i0 + j * 256;
            uint2 h = { pk2(v[j].x, v[j].y), pk2(v[j].z, v[j].w) };
            *(uint2*)&ws16[(size_t)dst + idx * 4] = h;
        }
        return;
    }

    const int lane = threadIdx.x & 63;
    const int wv   = threadIdx.x >> 6;
    const int b    = grp * 4 + wv;
    const int pd   = pdin[b];

    const float* a1 = prev_a + (size_t)b * 2048 + 1024;
    const float* b1 = prev_b + (size_t)b * 2048 + 1024;
    const float* xr = X + (size_t)b * 1024;

    int k;
    float fv;
    if (pd == 0) {
        k = 2; fv = 1.f;
    } else {
        float d0 = 0.f, d3 = 0.f;
        const float* w0 = w_att;
        const float* w3 = w_att + 3 * 8192;
        const float* u0 = u;
        const float* u3 = u + 2048;
#pragma unroll
        for (int uu = 0; uu < 2; ++uu) {
            const int c = lane * 16 + uu * 8;
#pragma unroll
            for (int q = 0; q < 2; ++q) {
                const int cc = c + q * 4;
                float4 av  = *(const float4*)&a1[cc];
                float4 bv  = *(const float4*)&b1[cc];
                float4 xv  = *(const float4*)&xr[cc];
                float4 ws0 = *(const float4*)&wsum[cc];          // = wa0+wc0
                float4 ws3 = *(const float4*)&wsum[1024 + cc];   // = wa3+wc3
                float4 wb0 = *(const float4*)&w0[3072 + cc];
                float4 wb3 = *(const float4*)&w3[3072 + cc];
                float4 ux0 = *(const float4*)&u0[cc];
                float4 ux3 = *(const float4*)&u3[cc];
                float4 ub0 = *(const float4*)&u0[1024 + cc];
                float4 ub3 = *(const float4*)&u3[1024 + cc];
                d0 += av.x*ws0.x + av.y*ws0.y + av.z*ws0.z + av.w*ws0.w;
                d3 += av.x*ws3.x + av.y*ws3.y + av.z*ws3.z + av.w*ws3.w;
                d0 += bv.x*wb0.x + bv.y*wb0.y + bv.z*wb0.z + bv.w*wb0.w;
                d3 += bv.x*wb3.x + bv.y*wb3.y + bv.z*wb3.z + bv.w*wb3.w;
                d0 += xv.x*ux0.x + xv.y*ux0.y + xv.z*ux0.z + xv.w*ux0.w;
                d3 += xv.x*ux3.x + xv.y*ux3.y + xv.z*ux3.z + xv.w*ux3.w;
                d0 += bv.x*ub0.x + bv.y*ub0.y + bv.z*ub0.z + bv.w*ub0.w;
                d3 += bv.x*ub3.x + bv.y*ub3.y + bv.z*ub3.z + bv.w*ub3.w;
            }
        }
#pragma unroll
        for (int off = 32; off; off >>= 1) {
            d0 += __shfl_xor(d0, off, 64);
            d3 += __shfl_xor(d3, off, 64);
        }
        k = (d3 > d0) ? 3 : 0;
        fv = (k == 3) ? 1.f : 0.f;
    }
    const float jv = (pd == 0) ? 0.f : fv;
    const int nd = (k == 2) ? pd + 1 : pd;

    if (k == 3) {
#pragma unroll
        for (int uu = 0; uu < 4; ++uu) {
            const int c = uu * 256 + lane * 4;
            *(float4*)&outA[(size_t)b * 2048 + 1024 + c] = *(const float4*)&a1[c];
        }
    }
    {
        // fused bf16 conversion of X/a1/b1 rows (sources L1/L2-hot;
        // bit-identical to the old convert_all output)
#pragma unroll
        for (int uu = 0; uu < 4; ++uu) {
            const int c = uu * 256 + lane * 4;
            float4 xv = *(const float4*)&xr[c];
            float4 av = *(const float4*)&a1[c];
            float4 bv = *(const float4*)&b1[c];
            uint2 hx = { pk2(xv.x, xv.y), pk2(xv.z, xv.w) };
            uint2 ha = { pk2(av.x, av.y), pk2(av.z, av.w) };
            uint2 hb = { pk2(bv.x, bv.y), pk2(bv.z, bv.w) };
            *(uint2*)&ws16[XB  + (size_t)b * 1024 + c] = hx;
            *(uint2*)&ws16[A1B + (size_t)b * 1024 + c] = ha;
            *(uint2*)&ws16[B1B + (size_t)b * 1024 + c] = hb;
        }
    }
    if (lane == 0) {
        kbuf[b] = k;
        const int j = (k == 0) ? 0 : (k == 2) ? 1 : 2;
        const int pos = atomicAdd(&cnt[j], 1);
        lists[j * 4096 + pos] = b;
        out[OUT_D_OFF + b] = (float)nd;
        out[OUT_F_OFF + b] = fv;
        out[OUT_J_OFF + b] = jv;
    }
}

// ================= fallback path (proven round-6 GEMM) =================
#define BMf 128
#define BNf 64
#define LDK 72

struct RegTile { float4 a[8]; float4 b[4]; };

__device__ __forceinline__ void load_tile(RegTile& s,
        const float* const* segp, const int* segs,
        const float* __restrict__ W, int K, int kn,
        int m0, int n0, int lr, int lc)
{
    const int seg = kn >> 4;
    const int kl  = (kn & 15) * 64;
    const float* ab = segp[seg];
    const int astr  = segs[seg];
#pragma unroll
    for (int i = 0; i < 8; ++i)
        s.a[i] = *(const float4*)(ab + (size_t)(m0 + i * 16 + lr) * astr + kl + lc);
#pragma unroll
    for (int i = 0; i < 4; ++i)
        s.b[i] = *(const float4*)(W + (size_t)(n0 + i * 16 + lr) * K + kn * 64 + lc);
}
__device__ __forceinline__ void stage_tile(const RegTile& s, u16* LA, u16* LB,
                                           int lr, int lc)
{
#pragma unroll
    for (int i = 0; i < 8; ++i) {
        uint2 h = { pk2(s.a[i].x, s.a[i].y), pk2(s.a[i].z, s.a[i].w) };
        *(uint2*)&LA[(i * 16 + lr) * LDK + lc] = h;
    }
#pragma unroll
    for (int i = 0; i < 4; ++i) {
        uint2 h = { pk2(s.b[i].x, s.b[i].y), pk2(s.b[i].z, s.b[i].w) };
        *(uint2*)&LB[(i * 16 + lr) * LDK + lc] = h;
    }
}
__device__ __forceinline__ void do_mfma_f(const u16* LA, const u16* LB,
                                          int wm, int wn, int lane, f32x4 acc[4][2])
{
#pragma unroll
    for (int ks = 0; ks < 2; ++ks) {
        const int kc = ks * 32 + (lane >> 4) * 8;
        frag8 af[4], bf[2];
#pragma unroll
        for (int i = 0; i < 4; ++i)
            af[i] = *(const frag8*)&LA[(wm * 64 + i * 16 + (lane & 15)) * LDK + kc];
#pragma unroll
        for (int j = 0; j < 2; ++j)
            bf[j] = *(const frag8*)&LB[(wn * 32 + j * 16 + (lane & 15)) * LDK + kc];
#pragma unroll
        for (int i = 0; i < 4; ++i)
#pragma unroll
            for (int j = 0; j < 2; ++j)
                acc[i][j] = __builtin_amdgcn_mfma_f32_16x16x32_bf16(af[i], bf[j], acc[i][j], 0, 0, 0);
    }
}

__global__ __launch_bounds__(256)
void gemm_k(const float* __restrict__ a0, int as0,
            const float* __restrict__ a1p, int as1,
            const float* __restrict__ a2p, int as2,
            const float* __restrict__ W, int K,
            const int* __restrict__ gate, int ksel,
            float* __restrict__ outp, int ostr)
{
    __shared__ alignas(16) u16 lsA[2][BMf * LDK];
    __shared__ alignas(16) u16 lsB[2][BNf * LDK];

    const int tid  = threadIdx.x;
    const int lane = tid & 63;
    const int wv   = tid >> 6;
    const int wm   = wv >> 1, wn = wv & 1;
    const int m0   = blockIdx.x * BMf;
    const int n0   = blockIdx.y * BNf;
    const int lr = tid >> 4;
    const int lc = (tid & 15) * 4;

    f32x4 acc[4][2];
#pragma unroll
    for (int i = 0; i < 4; ++i)
#pragma unroll
        for (int j = 0; j < 2; ++j) acc[i][j] = (f32x4){0.f, 0.f, 0.f, 0.f};

    const float* segp[3] = { a0, a1p, a2p };
    const int    segs[3] = { as0, as1, as2 };

    const int nkt = K / 64;
    RegTile S0, S1;
    load_tile(S0, segp, segs, W, K, 0, m0, n0, lr, lc);
    load_tile(S1, segp, segs, W, K, 1, m0, n0, lr, lc);
    stage_tile(S0, lsA[0], lsB[0], lr, lc);
    __syncthreads();

    for (int kt = 0; kt < nkt; kt += 2) {
        if (kt + 2 < nkt) load_tile(S0, segp, segs, W, K, kt + 2, m0, n0, lr, lc);
        do_mfma_f(lsA[0], lsB[0], wm, wn, lane, acc);
        stage_tile(S1, lsA[1], lsB[1], lr, lc);
        __syncthreads();
        if (kt + 3 < nkt) load_tile(S1, segp, segs, W, K, kt + 3, m0, n0, lr, lc);
        do_mfma_f(lsA[1], lsB[1], wm, wn, lane, acc);
        if (kt + 2 < nkt) {
            stage_tile(S0, lsA[0], lsB[0], lr, lc);
            __syncthreads();
        }
    }

    const int quad = lane >> 4;
    const int lcol = lane & 15;
#pragma unroll
    for (int i = 0; i < 4; ++i) {
#pragma unroll
        for (int r = 0; r < 4; ++r) {
            const int grow = m0 + wm * 64 + i * 16 + quad * 4 + r;
            if (gate[grow] == ksel) {
#pragma unroll
                for (int j = 0; j < 2; ++j) {
                    const int gcol = n0 + wn * 32 + j * 16 + lcol;
                    outp[(size_t)grow * ostr + gcol] = acc[i][j][r];
                }
            }
        }
    }
}

// ---------- prep_u + decide (fallback path only) ----------
__global__ __launch_bounds__(256)
void prep_u(const float* __restrict__ w_b11, const float* __restrict__ w_att,
            float* __restrict__ u)
{
    const int k  = (blockIdx.x & 7) * 256 + threadIdx.x;
    const int c0 = (blockIdx.x >> 3) * 16;
    float s0 = 0.f, s3 = 0.f;
    for (int c = c0; c < c0 + 16; ++c) {
        const float w = w_b11[(size_t)c * 2048 + k];
        s0 += w * w_att[7168 + c];
        s3 += w * w_att[3 * 8192 + 7168 + c];
    }
    atomicAdd(&u[k], s0);
    atomicAdd(&u[2048 + k], s3);
}

__global__ __launch_bounds__(256)
void decide(const float* __restrict__ X,
            const float* __restrict__ prev_a, const float* __restrict__ prev_b,
            const int* __restrict__ pdin,
            const float* __restrict__ w_att,
            const float* __restrict__ u,
            int* __restrict__ kbuf,
            float* __restrict__ out)
{
    const int lane = threadIdx.x & 63;
    const int wv   = threadIdx.x >> 6;
    const int b    = blockIdx.x * 4 + wv;
    const int pd   = pdin[b];

    const float* a1 = prev_a + (size_t)b * 2048 + 1024;
    const float* b1 = prev_b + (size_t)b * 2048 + 1024;
    const float* xr = X + (size_t)b * 1024;

    int k;
    float fv;
    if (pd == 0) {
        k = 2; fv = 1.f;
    } else {
        float d0 = 0.f, d3 = 0.f;
        const float* w0 = w_att;
        const float* w3 = w_att + 3 * 8192;
        const float* u0 = u;
        const float* u3 = u + 2048;
#pragma unroll
        for (int uu = 0; uu < 2; ++uu) {
            const int c = lane * 16 + uu * 8;
#pragma unroll
            for (int q = 0; q < 2; ++q) {
                const int cc = c + q * 4;
                float4 av = *(const float4*)&a1[cc];
                float4 bv = *(const float4*)&b1[cc];
                float4 xv = *(const float4*)&xr[cc];
                float4 wa0 = *(const float4*)&w0[2048 + cc];
                float4 wb0 = *(const float4*)&w0[3072 + cc];
                float4 wc0 = *(const float4*)&w0[6144 + cc];
                float4 wa3 = *(const float4*)&w3[2048 + cc];
                float4 wb3 = *(const float4*)&w3[3072 + cc];
                float4 wc3 = *(const float4*)&w3[6144 + cc];
                float4 ux0 = *(const float4*)&u0[cc];
                float4 ux3 = *(const float4*)&u3[cc];
                float4 ub0 = *(const float4*)&u0[1024 + cc];
                float4 ub3 = *(const float4*)&u3[1024 + cc];
                d0 += av.x*(wa0.x+wc0.x) + av.y*(wa0.y+wc0.y) + av.z*(wa0.z+wc0.z) + av.w*(wa0.w+wc0.w);
                d3 += av.x*(wa3.x+wc3.x) + av.y*(wa3.y+wc3.y) + av.z*(wa3.z+wc3.z) + av.w*(wa3.w+wc3.w);
                d0 += bv.x*wb0.x + bv.y*wb0.y + bv.z*wb0.z + bv.w*wb0.w;
                d3 += bv.x*wb3.x + bv.y*wb3.y + bv.z*wb3.z + bv.w*wb3.w;
                d0 += xv.x*ux0.x + xv.y*ux0.y + xv.z*ux0.z + xv.w*ux0.w;
                d3 += xv.x*ux3.x + xv.y*ux3.y + xv.z*ux3.z + xv.w*ux3.w;
                d0 += bv.x*ub0.x + bv.y*ub0.y + bv.z*ub0.z + bv.w*ub0.w;
                d3 += bv.x*ub3.x + bv.y*ub3.y + bv.z*ub3.z + bv.w*ub3.w;
            }
        }
#pragma unroll
        for (int off = 32; off; off >>= 1) {
            d0 += __shfl_xor(d0, off, 64);
            d3 += __shfl_xor(d3, off, 64);
        }
        k = (d3 > d0) ? 3 : 0;
        fv = (k == 3) ? 1.f : 0.f;
    }
    const float jv = (pd == 0) ? 0.f : fv;
    const int nd = (k == 2) ? pd + 1 : pd;

    float* outA = out;
    float* outB = out + OUT_B_OFF;

    const float4 z4 = make_float4(0.f, 0.f, 0.f, 0.f);
#pragma unroll
    for (int uu = 0; uu < 4; ++uu) {
        const int c = uu * 256 + lane * 4;
        *(float4*)&outA[(size_t)b * 2048 + c] = z4;
        *(float4*)&outB[(size_t)b * 2048 + c] = z4;
    }
    if (k == 3) {
#pragma unroll
        for (int uu = 0; uu < 4; ++uu) {
            const int c = uu * 256 + lane * 4;
            *(float4*)&outA[(size_t)b * 2048 + 1024 + c] = *(const float4*)&a1[c];
        }
    }
    if (lane == 0) {
        kbuf[b] = k;
        out[OUT_D_OFF + b] = (float)nd;
        out[OUT_F_OFF + b] = fv;
        out[OUT_J_OFF + b] = jv;
    }
}

// ---------- launch ----------
extern "C" void kernel_launch(void* const* d_in, const int* in_sizes, int n_in,
                              void* d_out, int out_size, void* d_ws, size_t ws_size,
                              hipStream_t stream)
{
    const float* X      = (const float*)d_in[0];
    const float* prev_a = (const float*)d_in[3];
    const float* prev_b = (const float*)d_in[4];
    const int*   pd     = (const int*)d_in[5];
    const float* w_a00  = (const float*)d_in[6];
    const float* w_a10  = (const float*)d_in[7];
    const float* w_b00  = (const float*)d_in[8];
    const float* w_b11  = (const float*)d_in[9];
    const float* w_b10  = (const float*)d_in[10];
    const float* w_att  = (const float*)d_in[12];

    float* u     = (float*)d_ws;                        // 16 KB
    float* wsum  = (float*)((char*)d_ws + WSUM_OFF);    // 8 KB
    int*   kbuf  = (int*)((char*)d_ws + KBUF_OFF);      // 16 KB
    int*   cnt   = (int*)((char*)d_ws + CNT_OFF);       // 16 B
    int*   lists = (int*)((char*)d_ws + LISTS_OFF);     // 48 KB
    u16*   ws16  = (u16*)((char*)d_ws + BF16_OFF);

    const float* a1 = prev_a + 1024;
    const float* b0 = prev_b;
    const float* b1 = prev_b + 1024;

    float* out   = (float*)d_out;
    float* outA1 = out + 1024;
    float* outB1 = out + OUT_B_OFF + 1024;

    dim3 blk(256);
    const bool fast = (ws_size >= WS_NEED);

    if (fast) {
        // memset covers u [0,16K) + cnt [40960,+16) (wsum/kbuf overwritten
        // before any read; lists bounded by cnt)
        hipMemsetAsync(d_ws, 0, CNT_OFF + 64, stream);
        prep<<<dim3(513), blk, 0, stream>>>(w_b11, w_att, u, wsum);
        decide_f<<<dim3(4096), blk, 0, stream>>>(X, prev_a, prev_b, pd,
            w_att, u, wsum, kbuf, lists, cnt, ws16, out,
            w_a00, w_a10, w_b00, w_b11, w_b10);

        int* l0 = lists;            // k==0 rows
        int* l2 = lists + 4096;     // k==2 rows
        int* l3 = lists + 8192;     // k==3 rows

        // Launch A (5 z): G1 (na00, k0), G2 (na10, k2),
        //   G4a (nb00 prefix [X,a1] -> fp32 partial in outB1),
        //   G3 (nb11, k3), G5a (nb10 prefix [X] -> partial in outB1).
        GPack p1;
        p1.d[0] = { XB, B0B, A1B, WA00B, NA00B,    3072, 3072, l0, &cnt[0], outA1, nullptr };
        p1.d[1] = { XB, B0B, 0u,  WA10B, NA10B,    2048, 2048, l2, &cnt[1], outA1, nullptr };
        p1.d[2] = { XB, A1B, 0u,  WB00B, NO_BCOPY, 2048, 3072, l0, &cnt[0], outB1, nullptr };
        p1.d[3] = { XB, B1B, 0u,  WB11B, NO_BCOPY, 2048, 2048, l3, &cnt[2], outB1, nullptr };
        p1.d[4] = { XB, 0u,  0u,  WB10B, NO_BCOPY, 1024, 2048, l2, &cnt[1], outB1, nullptr };
        gemm_gather<<<dim3(64, 16, 5), blk, 0, stream>>>(ws16, p1);

        // Launch B (2 z): G4b (nb00 suffix over na00, acc-init from partial),
        //   G5b (nb10 suffix over na10).  Exact fp32 accum order preserved.
        GPack p2;
        p2.d[0] = { NA00B, 0u, 0u, WB00B + 2048u, NO_BCOPY, 1024, 3072, l0, &cnt[0], outB1, outB1 };
        p2.d[1] = { NA10B, 0u, 0u, WB10B + 1024u, NO_BCOPY, 1024, 2048, l2, &cnt[1], outB1, outB1 };
        p2.d[2] = p2.d[0];   // unused (gridDim.z == 2)
        p2.d[3] = p2.d[0];
        p2.d[4] = p2.d[0];
        gemm_gather<<<dim3(64, 16, 2), blk, 0, stream>>>(ws16, p2);
    } else {
        // ---- fallback: proven round-6 fp32-staging path ----
        hipMemsetAsync(u, 0, 16384, stream);
        prep_u<<<dim3(512), blk, 0, stream>>>(w_b11, w_att, u);
        decide<<<dim3(Brows / 4), blk, 0, stream>>>(X, prev_a, prev_b, pd, w_att, u,
                                                    kbuf, out);
        dim3 grid(Brows / BMf, Hdim / BNf);
        gemm_k<<<grid, blk, 0, stream>>>(X, 1024, b0, 2048, a1, 2048,
                                         w_a00, 3072, kbuf, 0, outA1, 2048);
        gemm_k<<<grid, blk, 0, stream>>>(X, 1024, b0, 2048, nullptr, 0,
                                         w_a10, 2048, kbuf, 2, outA1, 2048);
        gemm_k<<<grid, blk, 0, stream>>>(X, 1024, b1, 2048, nullptr, 0,
                                         w_b11, 2048, pd, 1, outB1, 2048);
        gemm_k<<<grid, blk, 0, stream>>>(X, 1024, a1, 2048, outA1, 2048,
                                         w_b00, 3072, kbuf, 0, outB1, 2048);
        gemm_k<<<grid, blk, 0, stream>>>(X, 1024, outA1, 2048, nullptr, 0,
                                         w_b10, 2048, kbuf, 2, outB1, 2048);
    }
}

// Round 13
// 299.140 us; speedup vs baseline: 1.1492x; 1.1454x over previous
//
#include <hip/hip_runtime.h>
#include <hip/hip_bf16.h>
#include <stdint.h>
#include <math.h>

typedef unsigned short u16;
typedef __attribute__((ext_vector_type(8))) short frag8;   // 8 bf16 (4 VGPRs)
typedef __attribute__((ext_vector_type(4))) float f32x4;

#define Hdim 1024
#define Brows 4096

// out element offsets (fp32 elements)
#define OUT_B_OFF  8388608   // next_b base
#define OUT_D_OFF 16777216   // next_depth
#define OUT_F_OFF 16781312   // f
#define OUT_J_OFF 16785408   // j

// ---- workspace layout ----
// 0      .. 16K      : u (fp32 GEMV partial)        [memset 0]
// 16K    .. 24K      : wsum (2 x 1024 fp32: wa0+wc0, wa3+wc3)
// 24K    .. 40K      : kbuf (int per row)
// 40960  .. +16      : list counters (3 ints used)  [memset 0]
// 41024  .. +48K     : rowlists (3 x 4096 int, atomic-appended, cnt-bounded)
// 96K    ..          : bf16 region
#define WSUM_OFF  16384
#define KBUF_OFF  24576
#define CNT_OFF   40960
#define LISTS_OFF 41024
#define BF16_OFF  98304

// ---- bf16 workspace layout (u16-element offsets from ws+BF16_OFF) ----
#define XB      0u
#define B0B     4194304u
#define A1B     8388608u
#define B1B     12582912u
#define NA00B   16777216u
#define NA10B   20971520u
#define WA00B   25165824u   // 1024x3072
#define WA10B   28311552u   // 1024x2048
#define WB00B   30408704u   // 1024x3072
#define WB11B   33554432u   // 1024x2048
#define WB10B   35651584u   // 1024x2048
#define WS_BF_ELTS 37748736u
#define WS_NEED ((unsigned long long)BF16_OFF + (unsigned long long)WS_BF_ELTS * 2ull)

#define NO_BCOPY 0xFFFFFFFFu

__device__ __forceinline__ u16 f2bf(float f) {
    union { float f; unsigned int i; } v; v.f = f;
    unsigned int r = v.i + 0x7fffu + ((v.i >> 16) & 1u);   // RNE
    return (u16)(r >> 16);
}
__device__ __forceinline__ unsigned int pk2(float a, float b) {
    __hip_bfloat162 h = __float22bfloat162_rn(make_float2(a, b));
    union { __hip_bfloat162 h; unsigned int u; } v; v.h = h; return v.u;
}
__device__ __forceinline__ void gl_lds16(const u16* g, u16* l) {
    __builtin_amdgcn_global_load_lds(
        (const __attribute__((address_space(1))) unsigned int*)g,
        (__attribute__((address_space(3))) unsigned int*)l, 16, 0, 0);
}

// ================= fast path: gather-GEMM over compacted row lists =========
// (unchanged from r8 — XCD-locality swizzle verified +40%)
struct GDesc {
    unsigned int a0, a1s, a2;   // u16-elt offsets of A segments in ws16
    unsigned int w;             // weight offset (may point into a K-slice)
    unsigned int bcopy;         // u16-elt offset or NO_BCOPY
    int K;                      // K iteration extent (multiple of 64)
    int Kst;                    // W row stride in elements (>= K)
    const int* rows;            // row list (valid in [0,*pcnt))
    const int* pcnt;            // list length
    float* outp;
    const float* accp;          // null -> zero-init acc; else read partial
};
struct GPack { GDesc d[5]; };

__global__ __launch_bounds__(256)
void gemm_gather(u16* __restrict__ ws16, GPack gp)
{
    __shared__ alignas(16) u16 lsA[64 * 64];   // 8 KB
    __shared__ alignas(16) u16 lsB[64 * 64];   // 8 KB

    const GDesc g = gp.d[blockIdx.z];
    const int navail = *g.pcnt;

    // XCD-locality remap (bijective on the 64x16 plane)
    const int d  = blockIdx.y * 64 + blockIdx.x;
    const int s  = d >> 3;
    const int xp = ((s >> 4) << 3) | (d & 7);
    const int yp = s & 15;
    const int m0 = xp * 64;
    if (m0 >= navail) return;                   // empty tile (uniform)
    const int n0 = yp * 64;

    const int tid  = threadIdx.x;
    const int lane = tid & 63;
    const int wv   = tid >> 6;                  // wave -> n-subtile (16 cols)

    const int quad = lane >> 4;
    const int lcol = lane & 15;
    const int gcol = n0 + wv * 16 + lcol;

    int ridx[2];
#pragma unroll
    for (int i = 0; i < 2; ++i) {
        const int mi = m0 + (tid >> 3) + i * 32;
        ridx[i] = (mi < navail) ? g.rows[mi] : 0;
    }

    f32x4 acc[4];
#pragma unroll
    for (int i = 0; i < 4; ++i) acc[i] = (f32x4){0.f, 0.f, 0.f, 0.f};
    if (g.accp) {                               // continue earlier partial
#pragma unroll
        for (int i = 0; i < 4; ++i)
#pragma unroll
            for (int r = 0; r < 4; ++r) {
                const int mi = m0 + i * 16 + quad * 4 + r;
                if (mi < navail)
                    acc[i][r] = g.accp[(size_t)g.rows[mi] * 2048 + gcol];
            }
    }

    const u16* segp[3] = { ws16 + g.a0, ws16 + g.a1s, ws16 + g.a2 };
    const u16* W = ws16 + g.w;
    const int K = g.K;
    const int Kst = g.Kst;

    const int swz = ((tid & 7) ^ ((tid >> 3) & 7)) * 8;
    const int brow0 = tid >> 3;

    const int nkt = K / 64;
    for (int kt = 0; kt < nkt; ++kt) {
        const int seg = kt >> 4;
        const int kl  = (kt & 15) * 64;
        const u16* abase = segp[seg] + kl;
        const u16* wb = W + (size_t)n0 * Kst + kt * 64;
#pragma unroll
        for (int i = 0; i < 2; ++i)
            gl_lds16(abase + (size_t)ridx[i] * 1024 + swz, &lsA[(i * 256 + tid) * 8]);
#pragma unroll
        for (int i = 0; i < 2; ++i)
            gl_lds16(wb + (size_t)(i * 32 + brow0) * Kst + swz, &lsB[(i * 256 + tid) * 8]);
        __syncthreads();   // drains vmcnt -> LDS ready
#pragma unroll
        for (int ks = 0; ks < 2; ++ks) {
            const int kb = (ks * 32 + (lane >> 4) * 8) * 2;   // byte col offset
            frag8 af[4], bfr;
#pragma unroll
            for (int i = 0; i < 4; ++i) {
                const int ro = i * 16 + (lane & 15);
                af[i] = *(const frag8*)((const char*)lsA +
                            ((ro * 128 + kb) ^ ((ro & 7) << 4)));
            }
            {
                const int ro = wv * 16 + (lane & 15);
                bfr = *(const frag8*)((const char*)lsB +
                            ((ro * 128 + kb) ^ ((ro & 7) << 4)));
            }
#pragma unroll
            for (int i = 0; i < 4; ++i)
                acc[i] = __builtin_amdgcn_mfma_f32_16x16x32_bf16(af[i], bfr, acc[i], 0, 0, 0);
        }
        __syncthreads();   // readers done before next overwrite
    }

    // D layout: row = quad*4 + reg, col = lane&15 (m89-verified)
    u16* bc = (g.bcopy != NO_BCOPY) ? (ws16 + g.bcopy) : nullptr;
#pragma unroll
    for (int i = 0; i < 4; ++i) {
#pragma unroll
        for (int r = 0; r < 4; ++r) {
            const int mi = m0 + i * 16 + quad * 4 + r;
            if (mi >= navail) continue;         // list tail padding
            const int grow = g.rows[mi];
            const float v = acc[i][r];
            if (bc) bc[(size_t)grow * 1024 + gcol] = f2bf(v);
            g.outp[(size_t)grow * 2048 + gcol] = v;
        }
    }
}

// ---------- prep: u GEMV (blocks 0-511) + wsum precompute (block 512) ------
__global__ __launch_bounds__(256)
void prep(const float* __restrict__ w_b11, const float* __restrict__ w_att,
          float* __restrict__ u, float* __restrict__ wsum)
{
    const int bid = blockIdx.x;
    if (bid < 512) {
        const int k  = (bid & 7) * 256 + threadIdx.x;
        const int c0 = (bid >> 3) * 16;
        float s0 = 0.f, s3 = 0.f;
        for (int c = c0; c < c0 + 16; ++c) {
            const float w = w_b11[(size_t)c * 2048 + k];
            s0 += w * w_att[7168 + c];
            s3 += w * w_att[3 * 8192 + 7168 + c];
        }
        atomicAdd(&u[k], s0);
        atomicAdd(&u[2048 + k], s3);
        return;
    }
    const int c = threadIdx.x * 4;
    float4 a0 = *(const float4*)&w_att[2048 + c];
    float4 c0 = *(const float4*)&w_att[6144 + c];
    float4 a3 = *(const float4*)&w_att[3 * 8192 + 2048 + c];
    float4 c3 = *(const float4*)&w_att[3 * 8192 + 6144 + c];
    *(float4*)&wsum[c]        = make_float4(a0.x + c0.x, a0.y + c0.y, a0.z + c0.z, a0.w + c0.w);
    *(float4*)&wsum[1024 + c] = make_float4(a3.x + c3.x, a3.y + c3.y, a3.z + c3.z, a3.w + c3.w);
}

// ---------- decide_f: EXACT r10 revert (proven 71us / 298.7 total) ---------
// r11 (coarse streaming blocks + zero-fill move) and r12 (block-uniform
// batched loads) both regressed decide_f to ~115us.  Common factor: grid
// collapse 17408 -> 4096 blocks killed block-level TLP (occupancy 28 -> 11).
// r10 config: 17408 = 17*1024; per 17-block group, 16 x 1-float4 conversion
// blocks + 1 row block.  Row block: dot product + zero-fill + k3-copy +
// X/a1/b1 bf16 conversion + scalars.  decide_f streaming is now CLOSED as
// locally optimal.
__global__ __launch_bounds__(256, 4)
void decide_f(const float* __restrict__ X,
              const float* __restrict__ prev_a, const float* __restrict__ prev_b,
              const int* __restrict__ pdin,
              const float* __restrict__ w_att,
              const float* __restrict__ u,
              const float* __restrict__ wsum,
              int* __restrict__ kbuf,
              int* __restrict__ lists,
              int* __restrict__ cnt,
              u16* __restrict__ ws16,
              float* __restrict__ out,
              const float* __restrict__ wa00, const float* __restrict__ wa10,
              const float* __restrict__ wb00, const float* __restrict__ wb11,
              const float* __restrict__ wb10)
{
    const int grp = blockIdx.x / 17;
    const int sub = blockIdx.x % 17;
    if (sub != 16) {
        // ---- conversion path (one float4 per thread) ----
        long long gid = (long long)(grp * 16 + sub) * 256 + threadIdx.x;
        const float* src;
        unsigned int dst;
        long long idx;
        if (gid < 786432) {                         // wa00 (1024x3072)
            idx = gid;               src = wa00 + idx * 4; dst = WA00B;
        } else if (gid < 1310720) {                 // wa10 (1024x2048)
            idx = gid - 786432;      src = wa10 + idx * 4; dst = WA10B;
        } else if (gid < 2097152) {                 // wb00
            idx = gid - 1310720;     src = wb00 + idx * 4; dst = WB00B;
        } else if (gid < 2621440) {                 // wb11
            idx = gid - 2097152;     src = wb11 + idx * 4; dst = WB11B;
        } else if (gid < 3145728) {                 // wb10
            idx = gid - 2621440;     src = wb10 + idx * 4; dst = WB10B;
        } else {                                    // b0 (prev_b row-stride 2048)
            idx = gid - 3145728;
            src = prev_b + (idx >> 8) * 2048 + (idx & 255) * 4;      dst = B0B;
        }
        float4 v = *(const float4*)src;
        uint2 h = { pk2(v.x, v.y), pk2(v.z, v.w) };
        *(uint2*)&ws16[(size_t)dst + idx * 4] = h;
        return;
    }

    const int lane = threadIdx.x & 63;
    const int wv   = threadIdx.x >> 6;
    const int b    = grp * 4 + wv;
    const int pd   = pdin[b];

    const float* a1 = prev_a + (size_t)b * 2048 + 1024;
    const float* b1 = prev_b + (size_t)b * 2048 + 1024;
    const float* xr = X + (size_t)b * 1024;

    int k;
    float fv;
    if (pd == 0) {
        k = 2; fv = 1.f;
    } else {
        float d0 = 0.f, d3 = 0.f;
        const float* w0 = w_att;
        const float* w3 = w_att + 3 * 8192;
        const float* u0 = u;
        const float* u3 = u + 2048;
#pragma unroll
        for (int uu = 0; uu < 2; ++uu) {
            const int c = lane * 16 + uu * 8;
#pragma unroll
            for (int q = 0; q < 2; ++q) {
                const int cc = c + q * 4;
                float4 av  = *(const float4*)&a1[cc];
                float4 bv  = *(const float4*)&b1[cc];
                float4 xv  = *(const float4*)&xr[cc];
                float4 ws0 = *(const float4*)&wsum[cc];          // = wa0+wc0
                float4 ws3 = *(const float4*)&wsum[1024 + cc];   // = wa3+wc3
                float4 wb0 = *(const float4*)&w0[3072 + cc];
                float4 wb3 = *(const float4*)&w3[3072 + cc];
                float4 ux0 = *(const float4*)&u0[cc];
                float4 ux3 = *(const float4*)&u3[cc];
                float4 ub0 = *(const float4*)&u0[1024 + cc];
                float4 ub3 = *(const float4*)&u3[1024 + cc];
                d0 += av.x*ws0.x + av.y*ws0.y + av.z*ws0.z + av.w*ws0.w;
                d3 += av.x*ws3.x + av.y*ws3.y + av.z*ws3.z + av.w*ws3.w;
                d0 += bv.x*wb0.x + bv.y*wb0.y + bv.z*wb0.z + bv.w*wb0.w;
                d3 += bv.x*wb3.x + bv.y*wb3.y + bv.z*wb3.z + bv.w*wb3.w;
                d0 += xv.x*ux0.x + xv.y*ux0.y + xv.z*ux0.z + xv.w*ux0.w;
                d3 += xv.x*ux3.x + xv.y*ux3.y + xv.z*ux3.z + xv.w*ux3.w;
                d0 += bv.x*ub0.x + bv.y*ub0.y + bv.z*ub0.z + bv.w*ub0.w;
                d3 += bv.x*ub3.x + bv.y*ub3.y + bv.z*ub3.z + bv.w*ub3.w;
            }
        }
#pragma unroll
        for (int off = 32; off; off >>= 1) {
            d0 += __shfl_xor(d0, off, 64);
            d3 += __shfl_xor(d3, off, 64);
        }
        k = (d3 > d0) ? 3 : 0;
        fv = (k == 3) ? 1.f : 0.f;
    }
    const float jv = (pd == 0) ? 0.f : fv;
    const int nd = (k == 2) ? pd + 1 : pd;

    float* outA = out;
    float* outB = out + OUT_B_OFF;

    const float4 z4 = make_float4(0.f, 0.f, 0.f, 0.f);
#pragma unroll
    for (int uu = 0; uu < 4; ++uu) {
        const int c = uu * 256 + lane * 4;       // coalesced: 1KB/instr/wave
        *(float4*)&outA[(size_t)b * 2048 + c] = z4;
        *(float4*)&outB[(size_t)b * 2048 + c] = z4;
    }
    if (k == 3) {
#pragma unroll
        for (int uu = 0; uu < 4; ++uu) {
            const int c = uu * 256 + lane * 4;
            *(float4*)&outA[(size_t)b * 2048 + 1024 + c] = *(const float4*)&a1[c];
        }
    }
    {
        // fused bf16 conversion of X/a1/b1 rows (sources L1/L2-hot;
        // bit-identical to the old convert_all output)
#pragma unroll
        for (int uu = 0; uu < 4; ++uu) {
            const int c = uu * 256 + lane * 4;
            float4 xv = *(const float4*)&xr[c];
            float4 av = *(const float4*)&a1[c];
            float4 bv = *(const float4*)&b1[c];
            uint2 hx = { pk2(xv.x, xv.y), pk2(xv.z, xv.w) };
            uint2 ha = { pk2(av.x, av.y), pk2(av.z, av.w) };
            uint2 hb = { pk2(bv.x, bv.y), pk2(bv.z, bv.w) };
            *(uint2*)&ws16[XB  + (size_t)b * 1024 + c] = hx;
            *(uint2*)&ws16[A1B + (size_t)b * 1024 + c] = ha;
            *(uint2*)&ws16[B1B + (size_t)b * 1024 + c] = hb;
        }
    }
    if (lane == 0) {
        kbuf[b] = k;
        const int j = (k == 0) ? 0 : (k == 2) ? 1 : 2;
        const int pos = atomicAdd(&cnt[j], 1);
        lists[j * 4096 + pos] = b;
        out[OUT_D_OFF + b] = (float)nd;
        out[OUT_F_OFF + b] = fv;
        out[OUT_J_OFF + b] = jv;
    }
}

// ================= fallback path (proven round-6 GEMM) =================
#define BMf 128
#define BNf 64
#define LDK 72

struct RegTile { float4 a[8]; float4 b[4]; };

__device__ __forceinline__ void load_tile(RegTile& s,
        const float* const* segp, const int* segs,
        const float* __restrict__ W, int K, int kn,
        int m0, int n0, int lr, int lc)
{
    const int seg = kn >> 4;
    const int kl  = (kn & 15) * 64;
    const float* ab = segp[seg];
    const int astr  = segs[seg];
#pragma unroll
    for (int i = 0; i < 8; ++i)
        s.a[i] = *(const float4*)(ab + (size_t)(m0 + i * 16 + lr) * astr + kl + lc);
#pragma unroll
    for (int i = 0; i < 4; ++i)
        s.b[i] = *(const float4*)(W + (size_t)(n0 + i * 16 + lr) * K + kn * 64 + lc);
}
__device__ __forceinline__ void stage_tile(const RegTile& s, u16* LA, u16* LB,
                                           int lr, int lc)
{
#pragma unroll
    for (int i = 0; i < 8; ++i) {
        uint2 h = { pk2(s.a[i].x, s.a[i].y), pk2(s.a[i].z, s.a[i].w) };
        *(uint2*)&LA[(i * 16 + lr) * LDK + lc] = h;
    }
#pragma unroll
    for (int i = 0; i < 4; ++i) {
        uint2 h = { pk2(s.b[i].x, s.b[i].y), pk2(s.b[i].z, s.b[i].w) };
        *(uint2*)&LB[(i * 16 + lr) * LDK + lc] = h;
    }
}
__device__ __forceinline__ void do_mfma_f(const u16* LA, const u16* LB,
                                          int wm, int wn, int lane, f32x4 acc[4][2])
{
#pragma unroll
    for (int ks = 0; ks < 2; ++ks) {
        const int kc = ks * 32 + (lane >> 4) * 8;
        frag8 af[4], bf[2];
#pragma unroll
        for (int i = 0; i < 4; ++i)
            af[i] = *(const frag8*)&LA[(wm * 64 + i * 16 + (lane & 15)) * LDK + kc];
#pragma unroll
        for (int j = 0; j < 2; ++j)
            bf[j] = *(const frag8*)&LB[(wn * 32 + j * 16 + (lane & 15)) * LDK + kc];
#pragma unroll
        for (int i = 0; i < 4; ++i)
#pragma unroll
            for (int j = 0; j < 2; ++j)
                acc[i][j] = __builtin_amdgcn_mfma_f32_16x16x32_bf16(af[i], bf[j], acc[i][j], 0, 0, 0);
    }
}

__global__ __launch_bounds__(256)
void gemm_k(const float* __restrict__ a0, int as0,
            const float* __restrict__ a1p, int as1,
            const float* __restrict__ a2p, int as2,
            const float* __restrict__ W, int K,
            const int* __restrict__ gate, int ksel,
            float* __restrict__ outp, int ostr)
{
    __shared__ alignas(16) u16 lsA[2][BMf * LDK];
    __shared__ alignas(16) u16 lsB[2][BNf * LDK];

    const int tid  = threadIdx.x;
    const int lane = tid & 63;
    const int wv   = tid >> 6;
    const int wm   = wv >> 1, wn = wv & 1;
    const int m0   = blockIdx.x * BMf;
    const int n0   = blockIdx.y * BNf;
    const int lr = tid >> 4;
    const int lc = (tid & 15) * 4;

    f32x4 acc[4][2];
#pragma unroll
    for (int i = 0; i < 4; ++i)
#pragma unroll
        for (int j = 0; j < 2; ++j) acc[i][j] = (f32x4){0.f, 0.f, 0.f, 0.f};

    const float* segp[3] = { a0, a1p, a2p };
    const int    segs[3] = { as0, as1, as2 };

    const int nkt = K / 64;
    RegTile S0, S1;
    load_tile(S0, segp, segs, W, K, 0, m0, n0, lr, lc);
    load_tile(S1, segp, segs, W, K, 1, m0, n0, lr, lc);
    stage_tile(S0, lsA[0], lsB[0], lr, lc);
    __syncthreads();

    for (int kt = 0; kt < nkt; kt += 2) {
        if (kt + 2 < nkt) load_tile(S0, segp, segs, W, K, kt + 2, m0, n0, lr, lc);
        do_mfma_f(lsA[0], lsB[0], wm, wn, lane, acc);
        stage_tile(S1, lsA[1], lsB[1], lr, lc);
        __syncthreads();
        if (kt + 3 < nkt) load_tile(S1, segp, segs, W, K, kt + 3, m0, n0, lr, lc);
        do_mfma_f(lsA[1], lsB[1], wm, wn, lane, acc);
        if (kt + 2 < nkt) {
            stage_tile(S0, lsA[0], lsB[0], lr, lc);
            __syncthreads();
        }
    }

    const int quad = lane >> 4;
    const int lcol = lane & 15;
#pragma unroll
    for (int i = 0; i < 4; ++i) {
#pragma unroll
        for (int r = 0; r < 4; ++r) {
            const int grow = m0 + wm * 64 + i * 16 + quad * 4 + r;
            if (gate[grow] == ksel) {
#pragma unroll
                for (int j = 0; j < 2; ++j) {
                    const int gcol = n0 + wn * 32 + j * 16 + lcol;
                    outp[(size_t)grow * ostr + gcol] = acc[i][j][r];
                }
            }
        }
    }
}

// ---------- prep_u + decide (fallback path only) ----------
__global__ __launch_bounds__(256)
void prep_u(const float* __restrict__ w_b11, const float* __restrict__ w_att,
            float* __restrict__ u)
{
    const int k  = (blockIdx.x & 7) * 256 + threadIdx.x;
    const int c0 = (blockIdx.x >> 3) * 16;
    float s0 = 0.f, s3 = 0.f;
    for (int c = c0; c < c0 + 16; ++c) {
        const float w = w_b11[(size_t)c * 2048 + k];
        s0 += w * w_att[7168 + c];
        s3 += w * w_att[3 * 8192 + 7168 + c];
    }
    atomicAdd(&u[k], s0);
    atomicAdd(&u[2048 + k], s3);
}

__global__ __launch_bounds__(256)
void decide(const float* __restrict__ X,
            const float* __restrict__ prev_a, const float* __restrict__ prev_b,
            const int* __restrict__ pdin,
            const float* __restrict__ w_att,
            const float* __restrict__ u,
            int* __restrict__ kbuf,
            float* __restrict__ out)
{
    const int lane = threadIdx.x & 63;
    const int wv   = threadIdx.x >> 6;
    const int b    = blockIdx.x * 4 + wv;
    const int pd   = pdin[b];

    const float* a1 = prev_a + (size_t)b * 2048 + 1024;
    const float* b1 = prev_b + (size_t)b * 2048 + 1024;
    const float* xr = X + (size_t)b * 1024;

    int k;
    float fv;
    if (pd == 0) {
        k = 2; fv = 1.f;
    } else {
        float d0 = 0.f, d3 = 0.f;
        const float* w0 = w_att;
        const float* w3 = w_att + 3 * 8192;
        const float* u0 = u;
        const float* u3 = u + 2048;
#pragma unroll
        for (int uu = 0; uu < 2; ++uu) {
            const int c = lane * 16 + uu * 8;
#pragma unroll
            for (int q = 0; q < 2; ++q) {
                const int cc = c + q * 4;
                float4 av = *(const float4*)&a1[cc];
                float4 bv = *(const float4*)&b1[cc];
                float4 xv = *(const float4*)&xr[cc];
                float4 wa0 = *(const float4*)&w0[2048 + cc];
                float4 wb0 = *(const float4*)&w0[3072 + cc];
                float4 wc0 = *(const float4*)&w0[6144 + cc];
                float4 wa3 = *(const float4*)&w3[2048 + cc];
                float4 wb3 = *(const float4*)&w3[3072 + cc];
                float4 wc3 = *(const float4*)&w3[6144 + cc];
                float4 ux0 = *(const float4*)&u0[cc];
                float4 ux3 = *(const float4*)&u3[cc];
                float4 ub0 = *(const float4*)&u0[1024 + cc];
                float4 ub3 = *(const float4*)&u3[1024 + cc];
                d0 += av.x*(wa0.x+wc0.x) + av.y*(wa0.y+wc0.y) + av.z*(wa0.z+wc0.z) + av.w*(wa0.w+wc0.w);
                d3 += av.x*(wa3.x+wc3.x) + av.y*(wa3.y+wc3.y) + av.z*(wa3.z+wc3.z) + av.w*(wa3.w+wc3.w);
                d0 += bv.x*wb0.x + bv.y*wb0.y + bv.z*wb0.z + bv.w*wb0.w;
                d3 += bv.x*wb3.x + bv.y*wb3.y + bv.z*wb3.z + bv.w*wb3.w;
                d0 += xv.x*ux0.x + xv.y*ux0.y + xv.z*ux0.z + xv.w*ux0.w;
                d3 += xv.x*ux3.x + xv.y*ux3.y + xv.z*ux3.z + xv.w*ux3.w;
                d0 += bv.x*ub0.x + bv.y*ub0.y + bv.z*ub0.z + bv.w*ub0.w;
                d3 += bv.x*ub3.x + bv.y*ub3.y + bv.z*ub3.z + bv.w*ub3.w;
            }
        }
#pragma unroll
        for (int off = 32; off; off >>= 1) {
            d0 += __shfl_xor(d0, off, 64);
            d3 += __shfl_xor(d3, off, 64);
        }
        k = (d3 > d0) ? 3 : 0;
        fv = (k == 3) ? 1.f : 0.f;
    }
    const float jv = (pd == 0) ? 0.f : fv;
    const int nd = (k == 2) ? pd + 1 : pd;

    float* outA = out;
    float* outB = out + OUT_B_OFF;

    const float4 z4 = make_float4(0.f, 0.f, 0.f, 0.f);
#pragma unroll
    for (int uu = 0; uu < 4; ++uu) {
        const int c = uu * 256 + lane * 4;
        *(float4*)&outA[(size_t)b * 2048 + c] = z4;
        *(float4*)&outB[(size_t)b * 2048 + c] = z4;
    }
    if (k == 3) {
#pragma unroll
        for (int uu = 0; uu < 4; ++uu) {
            const int c = uu * 256 + lane * 4;
            *(float4*)&outA[(size_t)b * 2048 + 1024 + c] = *(const float4*)&a1[c];
        }
    }
    if (lane == 0) {
        kbuf[b] = k;
        out[OUT_D_OFF + b] = (float)nd;
        out[OUT_F_OFF + b] = fv;
        out[OUT_J_OFF + b] = jv;
    }
}

// ---------- launch ----------
extern "C" void kernel_launch(void* const* d_in, const int* in_sizes, int n_in,
                              void* d_out, int out_size, void* d_ws, size_t ws_size,
                              hipStream_t stream)
{
    const float* X      = (const float*)d_in[0];
    const float* prev_a = (const float*)d_in[3];
    const float* prev_b = (const float*)d_in[4];
    const int*   pd     = (const int*)d_in[5];
    const float* w_a00  = (const float*)d_in[6];
    const float* w_a10  = (const float*)d_in[7];
    const float* w_b00  = (const float*)d_in[8];
    const float* w_b11  = (const float*)d_in[9];
    const float* w_b10  = (const float*)d_in[10];
    const float* w_att  = (const float*)d_in[12];

    float* u     = (float*)d_ws;                        // 16 KB
    float* wsum  = (float*)((char*)d_ws + WSUM_OFF);    // 8 KB
    int*   kbuf  = (int*)((char*)d_ws + KBUF_OFF);      // 16 KB
    int*   cnt   = (int*)((char*)d_ws + CNT_OFF);       // 16 B
    int*   lists = (int*)((char*)d_ws + LISTS_OFF);     // 48 KB
    u16*   ws16  = (u16*)((char*)d_ws + BF16_OFF);

    const float* a1 = prev_a + 1024;
    const float* b0 = prev_b;
    const float* b1 = prev_b + 1024;

    float* out   = (float*)d_out;
    float* outA1 = out + 1024;
    float* outB1 = out + OUT_B_OFF + 1024;

    dim3 blk(256);
    const bool fast = (ws_size >= WS_NEED);

    if (fast) {
        // memset covers u [0,16K) + cnt [40960,+16) (wsum/kbuf overwritten
        // before any read; lists bounded by cnt)
        hipMemsetAsync(d_ws, 0, CNT_OFF + 64, stream);
        prep<<<dim3(513), blk, 0, stream>>>(w_b11, w_att, u, wsum);
        decide_f<<<dim3(17408), blk, 0, stream>>>(X, prev_a, prev_b, pd,
            w_att, u, wsum, kbuf, lists, cnt, ws16, out,
            w_a00, w_a10, w_b00, w_b11, w_b10);

        int* l0 = lists;            // k==0 rows
        int* l2 = lists + 4096;     // k==2 rows
        int* l3 = lists + 8192;     // k==3 rows

        // Launch A (5 z): G1 (na00, k0), G2 (na10, k2),
        //   G4a (nb00 prefix [X,a1] -> fp32 partial in outB1),
        //   G3 (nb11, k3), G5a (nb10 prefix [X] -> partial in outB1).
        GPack p1;
        p1.d[0] = { XB, B0B, A1B, WA00B, NA00B,    3072, 3072, l0, &cnt[0], outA1, nullptr };
        p1.d[1] = { XB, B0B, 0u,  WA10B, NA10B,    2048, 2048, l2, &cnt[1], outA1, nullptr };
        p1.d[2] = { XB, A1B, 0u,  WB00B, NO_BCOPY, 2048, 3072, l0, &cnt[0], outB1, nullptr };
        p1.d[3] = { XB, B1B, 0u,  WB11B, NO_BCOPY, 2048, 2048, l3, &cnt[2], outB1, nullptr };
        p1.d[4] = { XB, 0u,  0u,  WB10B, NO_BCOPY, 1024, 2048, l2, &cnt[1], outB1, nullptr };
        gemm_gather<<<dim3(64, 16, 5), blk, 0, stream>>>(ws16, p1);

        // Launch B (2 z): G4b (nb00 suffix over na00, acc-init from partial),
        //   G5b (nb10 suffix over na10).  Exact fp32 accum order preserved.
        GPack p2;
        p2.d[0] = { NA00B, 0u, 0u, WB00B + 2048u, NO_BCOPY, 1024, 3072, l0, &cnt[0], outB1, outB1 };
        p2.d[1] = { NA10B, 0u, 0u, WB10B + 1024u, NO_BCOPY, 1024, 2048, l2, &cnt[1], outB1, outB1 };
        p2.d[2] = p2.d[0];   // unused (gridDim.z == 2)
        p2.d[3] = p2.d[0];
        p2.d[4] = p2.d[0];
        gemm_gather<<<dim3(64, 16, 2), blk, 0, stream>>>(ws16, p2);
    } else {
        // ---- fallback: proven round-6 fp32-staging path ----
        hipMemsetAsync(u, 0, 16384, stream);
        prep_u<<<dim3(512), blk, 0, stream>>>(w_b11, w_att, u);
        decide<<<dim3(Brows / 4), blk, 0, stream>>>(X, prev_a, prev_b, pd, w_att, u,
                                                    kbuf, out);
        dim3 grid(Brows / BMf, Hdim / BNf);
        gemm_k<<<grid, blk, 0, stream>>>(X, 1024, b0, 2048, a1, 2048,
                                         w_a00, 3072, kbuf, 0, outA1, 2048);
        gemm_k<<<grid, blk, 0, stream>>>(X, 1024, b0, 2048, nullptr, 0,
                                         w_a10, 2048, kbuf, 2, outA1, 2048);
        gemm_k<<<grid, blk, 0, stream>>>(X, 1024, b1, 2048, nullptr, 0,
                                         w_b11, 2048, pd, 1, outB1, 2048);
        gemm_k<<<grid, blk, 0, stream>>>(X, 1024, a1, 2048, outA1, 2048,
                                         w_b00, 3072, kbuf, 0, outB1, 2048);
        gemm_k<<<grid, blk, 0, stream>>>(X, 1024, outA1, 2048, nullptr, 0,
                                         w_b10, 2048, kbuf, 2, outB1, 2048);
    }
}

// Round 14
// 295.740 us; speedup vs baseline: 1.1624x; 1.0115x over previous
//
#include <hip/hip_runtime.h>
#include <hip/hip_bf16.h>
#include <stdint.h>
#include <math.h>

typedef unsigned short u16;
typedef __attribute__((ext_vector_type(8))) short frag8;   // 8 bf16 (4 VGPRs)
typedef __attribute__((ext_vector_type(4))) float f32x4;

#define Hdim 1024
#define Brows 4096

// out element offsets (fp32 elements)
#define OUT_B_OFF  8388608   // next_b base
#define OUT_D_OFF 16777216   // next_depth
#define OUT_F_OFF 16781312   // f
#define OUT_J_OFF 16785408   // j

// ---- workspace layout ----
// 0      .. 16K      : u (fp32 GEMV partial)        [memset 0]
// 16K    .. 24K      : wsum (2 x 1024 fp32: wa0+wc0, wa3+wc3)
// 24K    .. 40K      : kbuf (int per row)
// 40960  .. +16      : list counters (3 ints used)  [memset 0]
// 41024  .. +48K     : rowlists (3 x 4096 int, atomic-appended, cnt-bounded)
// 96K    ..          : bf16 region
#define WSUM_OFF  16384
#define KBUF_OFF  24576
#define CNT_OFF   40960
#define LISTS_OFF 41024
#define BF16_OFF  98304

// ---- bf16 workspace layout (u16-element offsets from ws+BF16_OFF) ----
#define XB      0u
#define B0B     4194304u
#define A1B     8388608u
#define B1B     12582912u
#define NA00B   16777216u
#define NA10B   20971520u
#define WA00B   25165824u   // 1024x3072
#define WA10B   28311552u   // 1024x2048
#define WB00B   30408704u   // 1024x3072
#define WB11B   33554432u   // 1024x2048
#define WB10B   35651584u   // 1024x2048
#define WS_BF_ELTS 37748736u
#define WS_NEED ((unsigned long long)BF16_OFF + (unsigned long long)WS_BF_ELTS * 2ull)

#define NO_BCOPY 0xFFFFFFFFu

__device__ __forceinline__ u16 f2bf(float f) {
    union { float f; unsigned int i; } v; v.f = f;
    unsigned int r = v.i + 0x7fffu + ((v.i >> 16) & 1u);   // RNE
    return (u16)(r >> 16);
}
__device__ __forceinline__ unsigned int pk2(float a, float b) {
    __hip_bfloat162 h = __float22bfloat162_rn(make_float2(a, b));
    union { __hip_bfloat162 h; unsigned int u; } v; v.h = h; return v.u;
}
__device__ __forceinline__ void gl_lds16(const u16* g, u16* l) {
    __builtin_amdgcn_global_load_lds(
        (const __attribute__((address_space(1))) unsigned int*)g,
        (__attribute__((address_space(3))) unsigned int*)l, 16, 0, 0);
}

// ================= fast path: gather-GEMM over compacted row lists =========
// r14: BK 64 -> 128.  Per kt128: 8 gl_lds + ONE barrier-pair + 16 MFMA
// (was 2 barrier-pairs per 16 MFMA) -> drain amortized 2x (m233: the
// stage+wait+barrier pair dominates a 2-phase loop; r5/r6 proved wait
// FLAVOR is neutral, so reduce wait COUNT).  LDS 32 KB (5 blocks/CU cap;
// measured residency ~3.5 so no loss).  All K extents / W-slice offsets
// divisible by 128; 1024-row segments = 8 kt128, never straddled.
// MFMA k-order unchanged (ks=0..3 ascending) -> bit-identical.
// Swizzle: 16-chunk rows, source chunk c^(r&15), read
// (ro*256+kb)^((ro&15)<<4) — bijective, 2-way bank aliasing only (free).
// XCD-locality remap (r8, verified +40%): 16 same-A blocks per XCD.
struct GDesc {
    unsigned int a0, a1s, a2;   // u16-elt offsets of A segments in ws16
    unsigned int w;             // weight offset (may point into a K-slice)
    unsigned int bcopy;         // u16-elt offset or NO_BCOPY
    int K;                      // K iteration extent (multiple of 128)
    int Kst;                    // W row stride in elements (>= K)
    const int* rows;            // row list (valid in [0,*pcnt))
    const int* pcnt;            // list length
    float* outp;
    const float* accp;          // null -> zero-init acc; else read partial
};
struct GPack { GDesc d[5]; };

__global__ __launch_bounds__(256)
void gemm_gather(u16* __restrict__ ws16, GPack gp)
{
    __shared__ alignas(16) u16 lsA[64 * 128];   // 16 KB
    __shared__ alignas(16) u16 lsB[64 * 128];   // 16 KB

    const GDesc g = gp.d[blockIdx.z];
    const int navail = *g.pcnt;

    // XCD-locality remap (bijective on the 64x16 plane)
    const int d  = blockIdx.y * 64 + blockIdx.x;
    const int s  = d >> 3;
    const int xp = ((s >> 4) << 3) | (d & 7);
    const int yp = s & 15;
    const int m0 = xp * 64;
    if (m0 >= navail) return;                   // empty tile (uniform)
    const int n0 = yp * 64;

    const int tid  = threadIdx.x;
    const int lane = tid & 63;
    const int wv   = tid >> 6;                  // wave -> n-subtile (16 cols)

    const int quad = lane >> 4;
    const int lcol = lane & 15;
    const int gcol = n0 + wv * 16 + lcol;

    // per-thread A gather rows: chunk ch = i*256+tid -> tile row i*16+(tid>>4)
    int ridx[4];
#pragma unroll
    for (int i = 0; i < 4; ++i) {
        const int mi = m0 + (tid >> 4) + i * 16;
        ridx[i] = (mi < navail) ? g.rows[mi] : 0;
    }

    f32x4 acc[4];
#pragma unroll
    for (int i = 0; i < 4; ++i) acc[i] = (f32x4){0.f, 0.f, 0.f, 0.f};
    if (g.accp) {                               // continue earlier partial
#pragma unroll
        for (int i = 0; i < 4; ++i)
#pragma unroll
            for (int r = 0; r < 4; ++r) {
                const int mi = m0 + i * 16 + quad * 4 + r;
                if (mi < navail)
                    acc[i][r] = g.accp[(size_t)g.rows[mi] * 2048 + gcol];
            }
    }

    const u16* segp[3] = { ws16 + g.a0, ws16 + g.a1s, ws16 + g.a2 };
    const u16* W = ws16 + g.w;
    const int K = g.K;
    const int Kst = g.Kst;

    // 16-chunk (128-elt) rows: chunk col c = tid&15, row%16 = (tid>>4)&15
    const int swz = ((tid & 15) ^ ((tid >> 4) & 15)) * 8;
    const int brow0 = tid >> 4;                 // B tile row base (i*16 +)

    const int nkt = K / 128;
    for (int kt = 0; kt < nkt; ++kt) {
        const int seg = kt >> 3;                // 8 kt128 per 1024-seg
        const int kl  = (kt & 7) * 128;
        const u16* abase = segp[seg] + kl;
        const u16* wb = W + (size_t)n0 * Kst + kt * 128;
        // A: 64x128 bf16 = 1024 16B-chunks, 4/thread (gathered rows)
#pragma unroll
        for (int i = 0; i < 4; ++i)
            gl_lds16(abase + (size_t)ridx[i] * 1024 + swz, &lsA[(i * 256 + tid) * 8]);
        // B: 64x128 = 1024 chunks, 4/thread (contiguous, stride Kst)
#pragma unroll
        for (int i = 0; i < 4; ++i)
            gl_lds16(wb + (size_t)(i * 16 + brow0) * Kst + swz, &lsB[(i * 256 + tid) * 8]);
        __syncthreads();   // drains vmcnt -> LDS ready
#pragma unroll
        for (int ks = 0; ks < 4; ++ks) {
            const int kb = (ks * 32 + (lane >> 4) * 8) * 2;   // byte col offset
            frag8 af[4], bfr;
#pragma unroll
            for (int i = 0; i < 4; ++i) {
                const int ro = i * 16 + (lane & 15);
                af[i] = *(const frag8*)((const char*)lsA +
                            ((ro * 256 + kb) ^ ((ro & 15) << 4)));
            }
            {
                const int ro = wv * 16 + (lane & 15);
                bfr = *(const frag8*)((const char*)lsB +
                            ((ro * 256 + kb) ^ ((ro & 15) << 4)));
            }
#pragma unroll
            for (int i = 0; i < 4; ++i)
                acc[i] = __builtin_amdgcn_mfma_f32_16x16x32_bf16(af[i], bfr, acc[i], 0, 0, 0);
        }
        __syncthreads();   // readers done before next overwrite
    }

    // D layout: row = quad*4 + reg, col = lane&15 (m89-verified)
    u16* bc = (g.bcopy != NO_BCOPY) ? (ws16 + g.bcopy) : nullptr;
#pragma unroll
    for (int i = 0; i < 4; ++i) {
#pragma unroll
        for (int r = 0; r < 4; ++r) {
            const int mi = m0 + i * 16 + quad * 4 + r;
            if (mi >= navail) continue;         // list tail padding
            const int grow = g.rows[mi];
            const float v = acc[i][r];
            if (bc) bc[(size_t)grow * 1024 + gcol] = f2bf(v);
            g.outp[(size_t)grow * 2048 + gcol] = v;
        }
    }
}

// ---------- prep: u GEMV (blocks 0-511) + wsum precompute (block 512) ------
__global__ __launch_bounds__(256)
void prep(const float* __restrict__ w_b11, const float* __restrict__ w_att,
          float* __restrict__ u, float* __restrict__ wsum)
{
    const int bid = blockIdx.x;
    if (bid < 512) {
        const int k  = (bid & 7) * 256 + threadIdx.x;
        const int c0 = (bid >> 3) * 16;
        float s0 = 0.f, s3 = 0.f;
        for (int c = c0; c < c0 + 16; ++c) {
            const float w = w_b11[(size_t)c * 2048 + k];
            s0 += w * w_att[7168 + c];
            s3 += w * w_att[3 * 8192 + 7168 + c];
        }
        atomicAdd(&u[k], s0);
        atomicAdd(&u[2048 + k], s3);
        return;
    }
    const int c = threadIdx.x * 4;
    float4 a0 = *(const float4*)&w_att[2048 + c];
    float4 c0 = *(const float4*)&w_att[6144 + c];
    float4 a3 = *(const float4*)&w_att[3 * 8192 + 2048 + c];
    float4 c3 = *(const float4*)&w_att[3 * 8192 + 6144 + c];
    *(float4*)&wsum[c]        = make_float4(a0.x + c0.x, a0.y + c0.y, a0.z + c0.z, a0.w + c0.w);
    *(float4*)&wsum[1024 + c] = make_float4(a3.x + c3.x, a3.y + c3.y, a3.z + c3.z, a3.w + c3.w);
}

// ---------- decide_f: r10 config (proven 71us; streaming CLOSED) -----------
__global__ __launch_bounds__(256, 4)
void decide_f(const float* __restrict__ X,
              const float* __restrict__ prev_a, const float* __restrict__ prev_b,
              const int* __restrict__ pdin,
              const float* __restrict__ w_att,
              const float* __restrict__ u,
              const float* __restrict__ wsum,
              int* __restrict__ kbuf,
              int* __restrict__ lists,
              int* __restrict__ cnt,
              u16* __restrict__ ws16,
              float* __restrict__ out,
              const float* __restrict__ wa00, const float* __restrict__ wa10,
              const float* __restrict__ wb00, const float* __restrict__ wb11,
              const float* __restrict__ wb10)
{
    const int grp = blockIdx.x / 17;
    const int sub = blockIdx.x % 17;
    if (sub != 16) {
        // ---- conversion path (one float4 per thread) ----
        long long gid = (long long)(grp * 16 + sub) * 256 + threadIdx.x;
        const float* src;
        unsigned int dst;
        long long idx;
        if (gid < 786432) {                         // wa00 (1024x3072)
            idx = gid;               src = wa00 + idx * 4; dst = WA00B;
        } else if (gid < 1310720) {                 // wa10 (1024x2048)
            idx = gid - 786432;      src = wa10 + idx * 4; dst = WA10B;
        } else if (gid < 2097152) {                 // wb00
            idx = gid - 1310720;     src = wb00 + idx * 4; dst = WB00B;
        } else if (gid < 2621440) {                 // wb11
            idx = gid - 2097152;     src = wb11 + idx * 4; dst = WB11B;
        } else if (gid < 3145728) {                 // wb10
            idx = gid - 2621440;     src = wb10 + idx * 4; dst = WB10B;
        } else {                                    // b0 (prev_b row-stride 2048)
            idx = gid - 3145728;
            src = prev_b + (idx >> 8) * 2048 + (idx & 255) * 4;      dst = B0B;
        }
        float4 v = *(const float4*)src;
        uint2 h = { pk2(v.x, v.y), pk2(v.z, v.w) };
        *(uint2*)&ws16[(size_t)dst + idx * 4] = h;
        return;
    }

    const int lane = threadIdx.x & 63;
    const int wv   = threadIdx.x >> 6;
    const int b    = grp * 4 + wv;
    const int pd   = pdin[b];

    const float* a1 = prev_a + (size_t)b * 2048 + 1024;
    const float* b1 = prev_b + (size_t)b * 2048 + 1024;
    const float* xr = X + (size_t)b * 1024;

    int k;
    float fv;
    if (pd == 0) {
        k = 2; fv = 1.f;
    } else {
        float d0 = 0.f, d3 = 0.f;
        const float* w0 = w_att;
        const float* w3 = w_att + 3 * 8192;
        const float* u0 = u;
        const float* u3 = u + 2048;
#pragma unroll
        for (int uu = 0; uu < 2; ++uu) {
            const int c = lane * 16 + uu * 8;
#pragma unroll
            for (int q = 0; q < 2; ++q) {
                const int cc = c + q * 4;
                float4 av  = *(const float4*)&a1[cc];
                float4 bv  = *(const float4*)&b1[cc];
                float4 xv  = *(const float4*)&xr[cc];
                float4 ws0 = *(const float4*)&wsum[cc];          // = wa0+wc0
                float4 ws3 = *(const float4*)&wsum[1024 + cc];   // = wa3+wc3
                float4 wb0 = *(const float4*)&w0[3072 + cc];
                float4 wb3 = *(const float4*)&w3[3072 + cc];
                float4 ux0 = *(const float4*)&u0[cc];
                float4 ux3 = *(const float4*)&u3[cc];
                float4 ub0 = *(const float4*)&u0[1024 + cc];
                float4 ub3 = *(const float4*)&u3[1024 + cc];
                d0 += av.x*ws0.x + av.y*ws0.y + av.z*ws0.z + av.w*ws0.w;
                d3 += av.x*ws3.x + av.y*ws3.y + av.z*ws3.z + av.w*ws3.w;
                d0 += bv.x*wb0.x + bv.y*wb0.y + bv.z*wb0.z + bv.w*wb0.w;
                d3 += bv.x*wb3.x + bv.y*wb3.y + bv.z*wb3.z + bv.w*wb3.w;
                d0 += xv.x*ux0.x + xv.y*ux0.y + xv.z*ux0.z + xv.w*ux0.w;
                d3 += xv.x*ux3.x + xv.y*ux3.y + xv.z*ux3.z + xv.w*ux3.w;
                d0 += bv.x*ub0.x + bv.y*ub0.y + bv.z*ub0.z + bv.w*ub0.w;
                d3 += bv.x*ub3.x + bv.y*ub3.y + bv.z*ub3.z + bv.w*ub3.w;
            }
        }
#pragma unroll
        for (int off = 32; off; off >>= 1) {
            d0 += __shfl_xor(d0, off, 64);
            d3 += __shfl_xor(d3, off, 64);
        }
        k = (d3 > d0) ? 3 : 0;
        fv = (k == 3) ? 1.f : 0.f;
    }
    const float jv = (pd == 0) ? 0.f : fv;
    const int nd = (k == 2) ? pd + 1 : pd;

    float* outA = out;
    float* outB = out + OUT_B_OFF;

    const float4 z4 = make_float4(0.f, 0.f, 0.f, 0.f);
#pragma unroll
    for (int uu = 0; uu < 4; ++uu) {
        const int c = uu * 256 + lane * 4;       // coalesced: 1KB/instr/wave
        *(float4*)&outA[(size_t)b * 2048 + c] = z4;
        *(float4*)&outB[(size_t)b * 2048 + c] = z4;
    }
    if (k == 3) {
#pragma unroll
        for (int uu = 0; uu < 4; ++uu) {
            const int c = uu * 256 + lane * 4;
            *(float4*)&outA[(size_t)b * 2048 + 1024 + c] = *(const float4*)&a1[c];
        }
    }
    {
        // fused bf16 conversion of X/a1/b1 rows (sources L1/L2-hot;
        // bit-identical to the old convert_all output)
#pragma unroll
        for (int uu = 0; uu < 4; ++uu) {
            const int c = uu * 256 + lane * 4;
            float4 xv = *(const float4*)&xr[c];
            float4 av = *(const float4*)&a1[c];
            float4 bv = *(const float4*)&b1[c];
            uint2 hx = { pk2(xv.x, xv.y), pk2(xv.z, xv.w) };
            uint2 ha = { pk2(av.x, av.y), pk2(av.z, av.w) };
            uint2 hb = { pk2(bv.x, bv.y), pk2(bv.z, bv.w) };
            *(uint2*)&ws16[XB  + (size_t)b * 1024 + c] = hx;
            *(uint2*)&ws16[A1B + (size_t)b * 1024 + c] = ha;
            *(uint2*)&ws16[B1B + (size_t)b * 1024 + c] = hb;
        }
    }
    if (lane == 0) {
        kbuf[b] = k;
        const int j = (k == 0) ? 0 : (k == 2) ? 1 : 2;
        const int pos = atomicAdd(&cnt[j], 1);
        lists[j * 4096 + pos] = b;
        out[OUT_D_OFF + b] = (float)nd;
        out[OUT_F_OFF + b] = fv;
        out[OUT_J_OFF + b] = jv;
    }
}

// ================= fallback path (proven round-6 GEMM) =================
#define BMf 128
#define BNf 64
#define LDK 72

struct RegTile { float4 a[8]; float4 b[4]; };

__device__ __forceinline__ void load_tile(RegTile& s,
        const float* const* segp, const int* segs,
        const float* __restrict__ W, int K, int kn,
        int m0, int n0, int lr, int lc)
{
    const int seg = kn >> 4;
    const int kl  = (kn & 15) * 64;
    const float* ab = segp[seg];
    const int astr  = segs[seg];
#pragma unroll
    for (int i = 0; i < 8; ++i)
        s.a[i] = *(const float4*)(ab + (size_t)(m0 + i * 16 + lr) * astr + kl + lc);
#pragma unroll
    for (int i = 0; i < 4; ++i)
        s.b[i] = *(const float4*)(W + (size_t)(n0 + i * 16 + lr) * K + kn * 64 + lc);
}
__device__ __forceinline__ void stage_tile(const RegTile& s, u16* LA, u16* LB,
                                           int lr, int lc)
{
#pragma unroll
    for (int i = 0; i < 8; ++i) {
        uint2 h = { pk2(s.a[i].x, s.a[i].y), pk2(s.a[i].z, s.a[i].w) };
        *(uint2*)&LA[(i * 16 + lr) * LDK + lc] = h;
    }
#pragma unroll
    for (int i = 0; i < 4; ++i) {
        uint2 h = { pk2(s.b[i].x, s.b[i].y), pk2(s.b[i].z, s.b[i].w) };
        *(uint2*)&LB[(i * 16 + lr) * LDK + lc] = h;
    }
}
__device__ __forceinline__ void do_mfma_f(const u16* LA, const u16* LB,
                                          int wm, int wn, int lane, f32x4 acc[4][2])
{
#pragma unroll
    for (int ks = 0; ks < 2; ++ks) {
        const int kc = ks * 32 + (lane >> 4) * 8;
        frag8 af[4], bf[2];
#pragma unroll
        for (int i = 0; i < 4; ++i)
            af[i] = *(const frag8*)&LA[(wm * 64 + i * 16 + (lane & 15)) * LDK + kc];
#pragma unroll
        for (int j = 0; j < 2; ++j)
            bf[j] = *(const frag8*)&LB[(wn * 32 + j * 16 + (lane & 15)) * LDK + kc];
#pragma unroll
        for (int i = 0; i < 4; ++i)
#pragma unroll
            for (int j = 0; j < 2; ++j)
                acc[i][j] = __builtin_amdgcn_mfma_f32_16x16x32_bf16(af[i], bf[j], acc[i][j], 0, 0, 0);
    }
}

__global__ __launch_bounds__(256)
void gemm_k(const float* __restrict__ a0, int as0,
            const float* __restrict__ a1p, int as1,
            const float* __restrict__ a2p, int as2,
            const float* __restrict__ W, int K,
            const int* __restrict__ gate, int ksel,
            float* __restrict__ outp, int ostr)
{
    __shared__ alignas(16) u16 lsA[2][BMf * LDK];
    __shared__ alignas(16) u16 lsB[2][BNf * LDK];

    const int tid  = threadIdx.x;
    const int lane = tid & 63;
    const int wv   = tid >> 6;
    const int wm   = wv >> 1, wn = wv & 1;
    const int m0   = blockIdx.x * BMf;
    const int n0   = blockIdx.y * BNf;
    const int lr = tid >> 4;
    const int lc = (tid & 15) * 4;

    f32x4 acc[4][2];
#pragma unroll
    for (int i = 0; i < 4; ++i)
#pragma unroll
        for (int j = 0; j < 2; ++j) acc[i][j] = (f32x4){0.f, 0.f, 0.f, 0.f};

    const float* segp[3] = { a0, a1p, a2p };
    const int    segs[3] = { as0, as1, as2 };

    const int nkt = K / 64;
    RegTile S0, S1;
    load_tile(S0, segp, segs, W, K, 0, m0, n0, lr, lc);
    load_tile(S1, segp, segs, W, K, 1, m0, n0, lr, lc);
    stage_tile(S0, lsA[0], lsB[0], lr, lc);
    __syncthreads();

    for (int kt = 0; kt < nkt; kt += 2) {
        if (kt + 2 < nkt) load_tile(S0, segp, segs, W, K, kt + 2, m0, n0, lr, lc);
        do_mfma_f(lsA[0], lsB[0], wm, wn, lane, acc);
        stage_tile(S1, lsA[1], lsB[1], lr, lc);
        __syncthreads();
        if (kt + 3 < nkt) load_tile(S1, segp, segs, W, K, kt + 3, m0, n0, lr, lc);
        do_mfma_f(lsA[1], lsB[1], wm, wn, lane, acc);
        if (kt + 2 < nkt) {
            stage_tile(S0, lsA[0], lsB[0], lr, lc);
            __syncthreads();
        }
    }

    const int quad = lane >> 4;
    const int lcol = lane & 15;
#pragma unroll
    for (int i = 0; i < 4; ++i) {
#pragma unroll
        for (int r = 0; r < 4; ++r) {
            const int grow = m0 + wm * 64 + i * 16 + quad * 4 + r;
            if (gate[grow] == ksel) {
#pragma unroll
                for (int j = 0; j < 2; ++j) {
                    const int gcol = n0 + wn * 32 + j * 16 + lcol;
                    outp[(size_t)grow * ostr + gcol] = acc[i][j][r];
                }
            }
        }
    }
}

// ---------- prep_u + decide (fallback path only) ----------
__global__ __launch_bounds__(256)
void prep_u(const float* __restrict__ w_b11, const float* __restrict__ w_att,
            float* __restrict__ u)
{
    const int k  = (blockIdx.x & 7) * 256 + threadIdx.x;
    const int c0 = (blockIdx.x >> 3) * 16;
    float s0 = 0.f, s3 = 0.f;
    for (int c = c0; c < c0 + 16; ++c) {
        const float w = w_b11[(size_t)c * 2048 + k];
        s0 += w * w_att[7168 + c];
        s3 += w * w_att[3 * 8192 + 7168 + c];
    }
    atomicAdd(&u[k], s0);
    atomicAdd(&u[2048 + k], s3);
}

__global__ __launch_bounds__(256)
void decide(const float* __restrict__ X,
            const float* __restrict__ prev_a, const float* __restrict__ prev_b,
            const int* __restrict__ pdin,
            const float* __restrict__ w_att,
            const float* __restrict__ u,
            int* __restrict__ kbuf,
            float* __restrict__ out)
{
    const int lane = threadIdx.x & 63;
    const int wv   = threadIdx.x >> 6;
    const int b    = blockIdx.x * 4 + wv;
    const int pd   = pdin[b];

    const float* a1 = prev_a + (size_t)b * 2048 + 1024;
    const float* b1 = prev_b + (size_t)b * 2048 + 1024;
    const float* xr = X + (size_t)b * 1024;

    int k;
    float fv;
    if (pd == 0) {
        k = 2; fv = 1.f;
    } else {
        float d0 = 0.f, d3 = 0.f;
        const float* w0 = w_att;
        const float* w3 = w_att + 3 * 8192;
        const float* u0 = u;
        const float* u3 = u + 2048;
#pragma unroll
        for (int uu = 0; uu < 2; ++uu) {
            const int c = lane * 16 + uu * 8;
#pragma unroll
            for (int q = 0; q < 2; ++q) {
                const int cc = c + q * 4;
                float4 av = *(const float4*)&a1[cc];
                float4 bv = *(const float4*)&b1[cc];
                float4 xv = *(const float4*)&xr[cc];
                float4 wa0 = *(const float4*)&w0[2048 + cc];
                float4 wb0 = *(const float4*)&w0[3072 + cc];
                float4 wc0 = *(const float4*)&w0[6144 + cc];
                float4 wa3 = *(const float4*)&w3[2048 + cc];
                float4 wb3 = *(const float4*)&w3[3072 + cc];
                float4 wc3 = *(const float4*)&w3[6144 + cc];
                float4 ux0 = *(const float4*)&u0[cc];
                float4 ux3 = *(const float4*)&u3[cc];
                float4 ub0 = *(const float4*)&u0[1024 + cc];
                float4 ub3 = *(const float4*)&u3[1024 + cc];
                d0 += av.x*(wa0.x+wc0.x) + av.y*(wa0.y+wc0.y) + av.z*(wa0.z+wc0.z) + av.w*(wa0.w+wc0.w);
                d3 += av.x*(wa3.x+wc3.x) + av.y*(wa3.y+wc3.y) + av.z*(wa3.z+wc3.z) + av.w*(wa3.w+wc3.w);
                d0 += bv.x*wb0.x + bv.y*wb0.y + bv.z*wb0.z + bv.w*wb0.w;
                d3 += bv.x*wb3.x + bv.y*wb3.y + bv.z*wb3.z + bv.w*wb3.w;
                d0 += xv.x*ux0.x + xv.y*ux0.y + xv.z*ux0.z + xv.w*ux0.w;
                d3 += xv.x*ux3.x + xv.y*ux3.y + xv.z*ux3.z + xv.w*ux3.w;
                d0 += bv.x*ub0.x + bv.y*ub0.y + bv.z*ub0.z + bv.w*ub0.w;
                d3 += bv.x*ub3.x + bv.y*ub3.y + bv.z*ub3.z + bv.w*ub3.w;
            }
        }
#pragma unroll
        for (int off = 32; off; off >>= 1) {
            d0 += __shfl_xor(d0, off, 64);
            d3 += __shfl_xor(d3, off, 64);
        }
        k = (d3 > d0) ? 3 : 0;
        fv = (k == 3) ? 1.f : 0.f;
    }
    const float jv = (pd == 0) ? 0.f : fv;
    const int nd = (k == 2) ? pd + 1 : pd;

    float* outA = out;
    float* outB = out + OUT_B_OFF;

    const float4 z4 = make_float4(0.f, 0.f, 0.f, 0.f);
#pragma unroll
    for (int uu = 0; uu < 4; ++uu) {
        const int c = uu * 256 + lane * 4;
        *(float4*)&outA[(size_t)b * 2048 + c] = z4;
        *(float4*)&outB[(size_t)b * 2048 + c] = z4;
    }
    if (k == 3) {
#pragma unroll
        for (int uu = 0; uu < 4; ++uu) {
            const int c = uu * 256 + lane * 4;
            *(float4*)&outA[(size_t)b * 2048 + 1024 + c] = *(const float4*)&a1[c];
        }
    }
    if (lane == 0) {
        kbuf[b] = k;
        out[OUT_D_OFF + b] = (float)nd;
        out[OUT_F_OFF + b] = fv;
        out[OUT_J_OFF + b] = jv;
    }
}

// ---------- launch ----------
extern "C" void kernel_launch(void* const* d_in, const int* in_sizes, int n_in,
                              void* d_out, int out_size, void* d_ws, size_t ws_size,
                              hipStream_t stream)
{
    const float* X      = (const float*)d_in[0];
    const float* prev_a = (const float*)d_in[3];
    const float* prev_b = (const float*)d_in[4];
    const int*   pd     = (const int*)d_in[5];
    const float* w_a00  = (const float*)d_in[6];
    const float* w_a10  = (const float*)d_in[7];
    const float* w_b00  = (const float*)d_in[8];
    const float* w_b11  = (const float*)d_in[9];
    const float* w_b10  = (const float*)d_in[10];
    const float* w_att  = (const float*)d_in[12];

    float* u     = (float*)d_ws;                        // 16 KB
    float* wsum  = (float*)((char*)d_ws + WSUM_OFF);    // 8 KB
    int*   kbuf  = (int*)((char*)d_ws + KBUF_OFF);      // 16 KB
    int*   cnt   = (int*)((char*)d_ws + CNT_OFF);       // 16 B
    int*   lists = (int*)((char*)d_ws + LISTS_OFF);     // 48 KB
    u16*   ws16  = (u16*)((char*)d_ws + BF16_OFF);

    const float* a1 = prev_a + 1024;
    const float* b0 = prev_b;
    const float* b1 = prev_b + 1024;

    float* out   = (float*)d_out;
    float* outA1 = out + 1024;
    float* outB1 = out + OUT_B_OFF + 1024;

    dim3 blk(256);
    const bool fast = (ws_size >= WS_NEED);

    if (fast) {
        // memset covers u [0,16K) + cnt [40960,+16) (wsum/kbuf overwritten
        // before any read; lists bounded by cnt)
        hipMemsetAsync(d_ws, 0, CNT_OFF + 64, stream);
        prep<<<dim3(513), blk, 0, stream>>>(w_b11, w_att, u, wsum);
        decide_f<<<dim3(17408), blk, 0, stream>>>(X, prev_a, prev_b, pd,
            w_att, u, wsum, kbuf, lists, cnt, ws16, out,
            w_a00, w_a10, w_b00, w_b11, w_b10);

        int* l0 = lists;            // k==0 rows
        int* l2 = lists + 4096;     // k==2 rows
        int* l3 = lists + 8192;     // k==3 rows

        // Launch A (5 z): G1 (na00, k0), G2 (na10, k2),
        //   G4a (nb00 prefix [X,a1] -> fp32 partial in outB1),
        //   G3 (nb11, k3), G5a (nb10 prefix [X] -> partial in outB1).
        GPack p1;
        p1.d[0] = { XB, B0B, A1B, WA00B, NA00B,    3072, 3072, l0, &cnt[0], outA1, nullptr };
        p1.d[1] = { XB, B0B, 0u,  WA10B, NA10B,    2048, 2048, l2, &cnt[1], outA1, nullptr };
        p1.d[2] = { XB, A1B, 0u,  WB00B, NO_BCOPY, 2048, 3072, l0, &cnt[0], outB1, nullptr };
        p1.d[3] = { XB, B1B, 0u,  WB11B, NO_BCOPY, 2048, 2048, l3, &cnt[2], outB1, nullptr };
        p1.d[4] = { XB, 0u,  0u,  WB10B, NO_BCOPY, 1024, 2048, l2, &cnt[1], outB1, nullptr };
        gemm_gather<<<dim3(64, 16, 5), blk, 0, stream>>>(ws16, p1);

        // Launch B (2 z): G4b (nb00 suffix over na00, acc-init from partial),
        //   G5b (nb10 suffix over na10).  Exact fp32 accum order preserved.
        GPack p2;
        p2.d[0] = { NA00B, 0u, 0u, WB00B + 2048u, NO_BCOPY, 1024, 3072, l0, &cnt[0], outB1, outB1 };
        p2.d[1] = { NA10B, 0u, 0u, WB10B + 1024u, NO_BCOPY, 1024, 2048, l2, &cnt[1], outB1, outB1 };
        p2.d[2] = p2.d[0];   // unused (gridDim.z == 2)
        p2.d[3] = p2.d[0];
        p2.d[4] = p2.d[0];
        gemm_gather<<<dim3(64, 16, 2), blk, 0, stream>>>(ws16, p2);
    } else {
        // ---- fallback: proven round-6 fp32-staging path ----
        hipMemsetAsync(u, 0, 16384, stream);
        prep_u<<<dim3(512), blk, 0, stream>>>(w_b11, w_att, u);
        decide<<<dim3(Brows / 4), blk, 0, stream>>>(X, prev_a, prev_b, pd, w_att, u,
                                                    kbuf, out);
        dim3 grid(Brows / BMf, Hdim / BNf);
        gemm_k<<<grid, blk, 0, stream>>>(X, 1024, b0, 2048, a1, 2048,
                                         w_a00, 3072, kbuf, 0, outA1, 2048);
        gemm_k<<<grid, blk, 0, stream>>>(X, 1024, b0, 2048, nullptr, 0,
                                         w_a10, 2048, kbuf, 2, outA1, 2048);
        gemm_k<<<grid, blk, 0, stream>>>(X, 1024, b1, 2048, nullptr, 0,
                                         w_b11, 2048, pd, 1, outB1, 2048);
        gemm_k<<<grid, blk, 0, stream>>>(X, 1024, a1, 2048, outA1, 2048,
                                         w_b00, 3072, kbuf, 0, outB1, 2048);
        gemm_k<<<grid, blk, 0, stream>>>(X, 1024, outA1, 2048, nullptr, 0,
                                         w_b10, 2048, kbuf, 2, outB1, 2048);
    }
}

// Round 15
// 290.805 us; speedup vs baseline: 1.1821x; 1.0170x over previous
//
#include <hip/hip_runtime.h>
#include <hip/hip_bf16.h>
#include <stdint.h>
#include <math.h>

typedef unsigned short u16;
typedef __attribute__((ext_vector_type(8))) short frag8;   // 8 bf16 (4 VGPRs)
typedef __attribute__((ext_vector_type(4))) float f32x4;

#define Hdim 1024
#define Brows 4096

// out element offsets (fp32 elements)
#define OUT_B_OFF  8388608   // next_b base
#define OUT_D_OFF 16777216   // next_depth
#define OUT_F_OFF 16781312   // f
#define OUT_J_OFF 16785408   // j

// ---- workspace layout ----
#define WSUM_OFF  16384
#define KBUF_OFF  24576
#define CNT_OFF   40960
#define LISTS_OFF 41024
#define BF16_OFF  98304

// ---- bf16 workspace layout (u16-element offsets from ws+BF16_OFF) ----
#define XB      0u
#define B0B     4194304u
#define A1B     8388608u
#define B1B     12582912u
#define NA00B   16777216u
#define NA10B   20971520u
#define WA00B   25165824u   // 1024x3072
#define WA10B   28311552u   // 1024x2048
#define WB00B   30408704u   // 1024x3072
#define WB11B   33554432u   // 1024x2048
#define WB10B   35651584u   // 1024x2048
#define WS_BF_ELTS 37748736u
#define WS_NEED ((unsigned long long)BF16_OFF + (unsigned long long)WS_BF_ELTS * 2ull)

#define NO_BCOPY 0xFFFFFFFFu

__device__ __forceinline__ u16 f2bf(float f) {
    union { float f; unsigned int i; } v; v.f = f;
    unsigned int r = v.i + 0x7fffu + ((v.i >> 16) & 1u);   // RNE
    return (u16)(r >> 16);
}
__device__ __forceinline__ unsigned int pk2(float a, float b) {
    __hip_bfloat162 h = __float22bfloat162_rn(make_float2(a, b));
    union { __hip_bfloat162 h; unsigned int u; } v; v.h = h; return v.u;
}
__device__ __forceinline__ void gl_lds16(const u16* g, u16* l) {
    __builtin_amdgcn_global_load_lds(
        (const __attribute__((address_space(1))) unsigned int*)g,
        (__attribute__((address_space(3))) unsigned int*)l, 16, 0, 0);
}

// ================= fast path: gather-GEMM over compacted row lists =========
// (r14 BK=128 version — verified; XCD remap r8 verified +40%)
struct GDesc {
    unsigned int a0, a1s, a2;   // u16-elt offsets of A segments in ws16
    unsigned int w;             // weight offset (may point into a K-slice)
    unsigned int bcopy;         // u16-elt offset or NO_BCOPY
    int K;                      // K iteration extent (multiple of 128)
    int Kst;                    // W row stride in elements (>= K)
    const int* rows;            // row list (valid in [0,*pcnt))
    const int* pcnt;            // list length
    float* outp;
    const float* accp;          // null -> zero-init acc; else read partial
};
struct GPack { GDesc d[5]; };

__global__ __launch_bounds__(256)
void gemm_gather(u16* __restrict__ ws16, GPack gp)
{
    __shared__ alignas(16) u16 lsA[64 * 128];   // 16 KB
    __shared__ alignas(16) u16 lsB[64 * 128];   // 16 KB

    const GDesc g = gp.d[blockIdx.z];
    const int navail = *g.pcnt;

    // XCD-locality remap (bijective on the 64x16 plane)
    const int d  = blockIdx.y * 64 + blockIdx.x;
    const int s  = d >> 3;
    const int xp = ((s >> 4) << 3) | (d & 7);
    const int yp = s & 15;
    const int m0 = xp * 64;
    if (m0 >= navail) return;                   // empty tile (uniform)
    const int n0 = yp * 64;

    const int tid  = threadIdx.x;
    const int lane = tid & 63;
    const int wv   = tid >> 6;                  // wave -> n-subtile (16 cols)

    const int quad = lane >> 4;
    const int lcol = lane & 15;
    const int gcol = n0 + wv * 16 + lcol;

    // per-thread A gather rows: chunk ch = i*256+tid -> tile row i*16+(tid>>4)
    int ridx[4];
#pragma unroll
    for (int i = 0; i < 4; ++i) {
        const int mi = m0 + (tid >> 4) + i * 16;
        ridx[i] = (mi < navail) ? g.rows[mi] : 0;
    }

    f32x4 acc[4];
#pragma unroll
    for (int i = 0; i < 4; ++i) acc[i] = (f32x4){0.f, 0.f, 0.f, 0.f};
    if (g.accp) {                               // continue earlier partial
#pragma unroll
        for (int i = 0; i < 4; ++i)
#pragma unroll
            for (int r = 0; r < 4; ++r) {
                const int mi = m0 + i * 16 + quad * 4 + r;
                if (mi < navail)
                    acc[i][r] = g.accp[(size_t)g.rows[mi] * 2048 + gcol];
            }
    }

    const u16* segp[3] = { ws16 + g.a0, ws16 + g.a1s, ws16 + g.a2 };
    const u16* W = ws16 + g.w;
    const int K = g.K;
    const int Kst = g.Kst;

    // 16-chunk (128-elt) rows: chunk col c = tid&15, row%16 = (tid>>4)&15
    const int swz = ((tid & 15) ^ ((tid >> 4) & 15)) * 8;
    const int brow0 = tid >> 4;                 // B tile row base (i*16 +)

    const int nkt = K / 128;
    for (int kt = 0; kt < nkt; ++kt) {
        const int seg = kt >> 3;                // 8 kt128 per 1024-seg
        const int kl  = (kt & 7) * 128;
        const u16* abase = segp[seg] + kl;
        const u16* wb = W + (size_t)n0 * Kst + kt * 128;
#pragma unroll
        for (int i = 0; i < 4; ++i)
            gl_lds16(abase + (size_t)ridx[i] * 1024 + swz, &lsA[(i * 256 + tid) * 8]);
#pragma unroll
        for (int i = 0; i < 4; ++i)
            gl_lds16(wb + (size_t)(i * 16 + brow0) * Kst + swz, &lsB[(i * 256 + tid) * 8]);
        __syncthreads();   // drains vmcnt -> LDS ready
#pragma unroll
        for (int ks = 0; ks < 4; ++ks) {
            const int kb = (ks * 32 + (lane >> 4) * 8) * 2;   // byte col offset
            frag8 af[4], bfr;
#pragma unroll
            for (int i = 0; i < 4; ++i) {
                const int ro = i * 16 + (lane & 15);
                af[i] = *(const frag8*)((const char*)lsA +
                            ((ro * 256 + kb) ^ ((ro & 15) << 4)));
            }
            {
                const int ro = wv * 16 + (lane & 15);
                bfr = *(const frag8*)((const char*)lsB +
                            ((ro * 256 + kb) ^ ((ro & 15) << 4)));
            }
#pragma unroll
            for (int i = 0; i < 4; ++i)
                acc[i] = __builtin_amdgcn_mfma_f32_16x16x32_bf16(af[i], bfr, acc[i], 0, 0, 0);
        }
        __syncthreads();   // readers done before next overwrite
    }

    // D layout: row = quad*4 + reg, col = lane&15 (m89-verified)
    u16* bc = (g.bcopy != NO_BCOPY) ? (ws16 + g.bcopy) : nullptr;
#pragma unroll
    for (int i = 0; i < 4; ++i) {
#pragma unroll
        for (int r = 0; r < 4; ++r) {
            const int mi = m0 + i * 16 + quad * 4 + r;
            if (mi >= navail) continue;         // list tail padding
            const int grow = g.rows[mi];
            const float v = acc[i][r];
            if (bc) bc[(size_t)grow * 1024 + gcol] = f2bf(v);
            g.outp[(size_t)grow * 2048 + gcol] = v;
        }
    }
}

// ---------- prep: u GEMV (blocks 0-511) + wsum precompute (block 512) ------
__global__ __launch_bounds__(256)
void prep(const float* __restrict__ w_b11, const float* __restrict__ w_att,
          float* __restrict__ u, float* __restrict__ wsum)
{
    const int bid = blockIdx.x;
    if (bid < 512) {
        const int k  = (bid & 7) * 256 + threadIdx.x;
        const int c0 = (bid >> 3) * 16;
        float s0 = 0.f, s3 = 0.f;
        for (int c = c0; c < c0 + 16; ++c) {
            const float w = w_b11[(size_t)c * 2048 + k];
            s0 += w * w_att[7168 + c];
            s3 += w * w_att[3 * 8192 + 7168 + c];
        }
        atomicAdd(&u[k], s0);
        atomicAdd(&u[2048 + k], s3);
        return;
    }
    const int c = threadIdx.x * 4;
    float4 a0 = *(const float4*)&w_att[2048 + c];
    float4 c0 = *(const float4*)&w_att[6144 + c];
    float4 a3 = *(const float4*)&w_att[3 * 8192 + 2048 + c];
    float4 c3 = *(const float4*)&w_att[3 * 8192 + 6144 + c];
    *(float4*)&wsum[c]        = make_float4(a0.x + c0.x, a0.y + c0.y, a0.z + c0.z, a0.w + c0.w);
    *(float4*)&wsum[1024 + c] = make_float4(a3.x + c3.x, a3.y + c3.y, a3.z + c3.z, a3.w + c3.w);
}

// ---------- decide_f: r10 grid + LDS-staged shared streams (r15) -----------
// The 8 shared dot-product streams (ws0,ws3,wb0,wb3,ux0,ux3,ub0,ub3 = 32KB)
// are identical for ALL rows; r14 had every row-wave re-load them from
// cache, paying ~8 serial latency batches/wave (62us row floor).  r15: row
// blocks stage them into LDS once (layout [stream][uuq][lane] -> staging
// loads AND ds_read_b128s contiguous across lanes, conflict-free, stream
// index compile-time since tid<256).  Dot loop now issues only the 3
// per-row streams (12 independent loads -> 1-2 latency exposures) + LDS
// reads.  SAME floats, SAME FMA order -> bit-identical.  Conversion blocks
// return before any LDS/barrier use.  LDS 32KB caps residency at 5
// blocks/CU (measured time-avg 2.15 -> cap shouldn't bind).
__global__ __launch_bounds__(256, 4)
void decide_f(const float* __restrict__ X,
              const float* __restrict__ prev_a, const float* __restrict__ prev_b,
              const int* __restrict__ pdin,
              const float* __restrict__ w_att,
              const float* __restrict__ u,
              const float* __restrict__ wsum,
              int* __restrict__ kbuf,
              int* __restrict__ lists,
              int* __restrict__ cnt,
              u16* __restrict__ ws16,
              float* __restrict__ out,
              const float* __restrict__ wa00, const float* __restrict__ wa10,
              const float* __restrict__ wb00, const float* __restrict__ wb11,
              const float* __restrict__ wb10)
{
    __shared__ alignas(16) float4 shs[2048];    // 8 streams x 256 f4 = 32KB

    const int grp = blockIdx.x / 17;
    const int sub = blockIdx.x % 17;
    if (sub != 16) {
        // ---- conversion path (one float4 per thread; no LDS/barrier) ----
        long long gid = (long long)(grp * 16 + sub) * 256 + threadIdx.x;
        const float* src;
        unsigned int dst;
        long long idx;
        if (gid < 786432) {                         // wa00 (1024x3072)
            idx = gid;               src = wa00 + idx * 4; dst = WA00B;
        } else if (gid < 1310720) {                 // wa10 (1024x2048)
            idx = gid - 786432;      src = wa10 + idx * 4; dst = WA10B;
        } else if (gid < 2097152) {                 // wb00
            idx = gid - 1310720;     src = wb00 + idx * 4; dst = WB00B;
        } else if (gid < 2621440) {                 // wb11
            idx = gid - 2097152;     src = wb11 + idx * 4; dst = WB11B;
        } else if (gid < 3145728) {                 // wb10
            idx = gid - 2621440;     src = wb10 + idx * 4; dst = WB10B;
        } else {                                    // b0 (prev_b row-stride 2048)
            idx = gid - 3145728;
            src = prev_b + (idx >> 8) * 2048 + (idx & 255) * 4;      dst = B0B;
        }
        float4 v = *(const float4*)src;
        uint2 h = { pk2(v.x, v.y), pk2(v.z, v.w) };
        *(uint2*)&ws16[(size_t)dst + idx * 4] = h;
        return;
    }

    // ---- row block: stage shared streams into LDS (block-cooperative) ----
    {
        const int tid = threadIdx.x;
        const float* sbase[8] = { wsum, wsum + 1024,
                                  w_att + 3072, w_att + 3 * 8192 + 3072,
                                  u, u + 2048, u + 1024, u + 3072 };
#pragma unroll
        for (int j = 0; j < 8; ++j) {   // stream index compile-time (tid<256)
            shs[j * 256 + (tid & 3) * 64 + (tid >> 2)] =
                *(const float4*)&sbase[j][tid * 4];
        }
    }
    __syncthreads();

    const int lane = threadIdx.x & 63;
    const int wv   = threadIdx.x >> 6;
    const int b    = grp * 4 + wv;
    const int pd   = pdin[b];

    const float* a1 = prev_a + (size_t)b * 2048 + 1024;
    const float* b1 = prev_b + (size_t)b * 2048 + 1024;
    const float* xr = X + (size_t)b * 1024;

    int k;
    float fv;
    if (pd == 0) {
        k = 2; fv = 1.f;
    } else {
        float d0 = 0.f, d3 = 0.f;
#pragma unroll
        for (int uu = 0; uu < 2; ++uu) {
#pragma unroll
            for (int q = 0; q < 2; ++q) {
                const int cc = lane * 16 + uu * 8 + q * 4;
                const int so = (uu * 2 + q) * 64 + lane;
                float4 av  = *(const float4*)&a1[cc];
                float4 bv  = *(const float4*)&b1[cc];
                float4 xv  = *(const float4*)&xr[cc];
                float4 ws0 = shs[0 * 256 + so];
                float4 ws3 = shs[1 * 256 + so];
                float4 wb0 = shs[2 * 256 + so];
                float4 wb3 = shs[3 * 256 + so];
                float4 ux0 = shs[4 * 256 + so];
                float4 ux3 = shs[5 * 256 + so];
                float4 ub0 = shs[6 * 256 + so];
                float4 ub3 = shs[7 * 256 + so];
                d0 += av.x*ws0.x + av.y*ws0.y + av.z*ws0.z + av.w*ws0.w;
                d3 += av.x*ws3.x + av.y*ws3.y + av.z*ws3.z + av.w*ws3.w;
                d0 += bv.x*wb0.x + bv.y*wb0.y + bv.z*wb0.z + bv.w*wb0.w;
                d3 += bv.x*wb3.x + bv.y*wb3.y + bv.z*wb3.z + bv.w*wb3.w;
                d0 += xv.x*ux0.x + xv.y*ux0.y + xv.z*ux0.z + xv.w*ux0.w;
                d3 += xv.x*ux3.x + xv.y*ux3.y + xv.z*ux3.z + xv.w*ux3.w;
                d0 += bv.x*ub0.x + bv.y*ub0.y + bv.z*ub0.z + bv.w*ub0.w;
                d3 += bv.x*ub3.x + bv.y*ub3.y + bv.z*ub3.z + bv.w*ub3.w;
            }
        }
#pragma unroll
        for (int off = 32; off; off >>= 1) {
            d0 += __shfl_xor(d0, off, 64);
            d3 += __shfl_xor(d3, off, 64);
        }
        k = (d3 > d0) ? 3 : 0;
        fv = (k == 3) ? 1.f : 0.f;
    }
    const float jv = (pd == 0) ? 0.f : fv;
    const int nd = (k == 2) ? pd + 1 : pd;

    float* outA = out;
    float* outB = out + OUT_B_OFF;

    const float4 z4 = make_float4(0.f, 0.f, 0.f, 0.f);
#pragma unroll
    for (int uu = 0; uu < 4; ++uu) {
        const int c = uu * 256 + lane * 4;       // coalesced: 1KB/instr/wave
        *(float4*)&outA[(size_t)b * 2048 + c] = z4;
        *(float4*)&outB[(size_t)b * 2048 + c] = z4;
    }
    if (k == 3) {
#pragma unroll
        for (int uu = 0; uu < 4; ++uu) {
            const int c = uu * 256 + lane * 4;
            *(float4*)&outA[(size_t)b * 2048 + 1024 + c] = *(const float4*)&a1[c];
        }
    }
    {
        // fused bf16 conversion of X/a1/b1 rows (sources L1/L2-hot;
        // bit-identical to the old convert_all output)
#pragma unroll
        for (int uu = 0; uu < 4; ++uu) {
            const int c = uu * 256 + lane * 4;
            float4 xv = *(const float4*)&xr[c];
            float4 av = *(const float4*)&a1[c];
            float4 bv = *(const float4*)&b1[c];
            uint2 hx = { pk2(xv.x, xv.y), pk2(xv.z, xv.w) };
            uint2 ha = { pk2(av.x, av.y), pk2(av.z, av.w) };
            uint2 hb = { pk2(bv.x, bv.y), pk2(bv.z, bv.w) };
            *(uint2*)&ws16[XB  + (size_t)b * 1024 + c] = hx;
            *(uint2*)&ws16[A1B + (size_t)b * 1024 + c] = ha;
            *(uint2*)&ws16[B1B + (size_t)b * 1024 + c] = hb;
        }
    }
    if (lane == 0) {
        kbuf[b] = k;
        const int j = (k == 0) ? 0 : (k == 2) ? 1 : 2;
        const int pos = atomicAdd(&cnt[j], 1);
        lists[j * 4096 + pos] = b;
        out[OUT_D_OFF + b] = (float)nd;
        out[OUT_F_OFF + b] = fv;
        out[OUT_J_OFF + b] = jv;
    }
}

// ================= fallback path (proven round-6 GEMM) =================
#define BMf 128
#define BNf 64
#define LDK 72

struct RegTile { float4 a[8]; float4 b[4]; };

__device__ __forceinline__ void load_tile(RegTile& s,
        const float* const* segp, const int* segs,
        const float* __restrict__ W, int K, int kn,
        int m0, int n0, int lr, int lc)
{
    const int seg = kn >> 4;
    const int kl  = (kn & 15) * 64;
    const float* ab = segp[seg];
    const int astr  = segs[seg];
#pragma unroll
    for (int i = 0; i < 8; ++i)
        s.a[i] = *(const float4*)(ab + (size_t)(m0 + i * 16 + lr) * astr + kl + lc);
#pragma unroll
    for (int i = 0; i < 4; ++i)
        s.b[i] = *(const float4*)(W + (size_t)(n0 + i * 16 + lr) * K + kn * 64 + lc);
}
__device__ __forceinline__ void stage_tile(const RegTile& s, u16* LA, u16* LB,
                                           int lr, int lc)
{
#pragma unroll
    for (int i = 0; i < 8; ++i) {
        uint2 h = { pk2(s.a[i].x, s.a[i].y), pk2(s.a[i].z, s.a[i].w) };
        *(uint2*)&LA[(i * 16 + lr) * LDK + lc] = h;
    }
#pragma unroll
    for (int i = 0; i < 4; ++i) {
        uint2 h = { pk2(s.b[i].x, s.b[i].y), pk2(s.b[i].z, s.b[i].w) };
        *(uint2*)&LB[(i * 16 + lr) * LDK + lc] = h;
    }
}
__device__ __forceinline__ void do_mfma_f(const u16* LA, const u16* LB,
                                          int wm, int wn, int lane, f32x4 acc[4][2])
{
#pragma unroll
    for (int ks = 0; ks < 2; ++ks) {
        const int kc = ks * 32 + (lane >> 4) * 8;
        frag8 af[4], bf[2];
#pragma unroll
        for (int i = 0; i < 4; ++i)
            af[i] = *(const frag8*)&LA[(wm * 64 + i * 16 + (lane & 15)) * LDK + kc];
#pragma unroll
        for (int j = 0; j < 2; ++j)
            bf[j] = *(const frag8*)&LB[(wn * 32 + j * 16 + (lane & 15)) * LDK + kc];
#pragma unroll
        for (int i = 0; i < 4; ++i)
#pragma unroll
            for (int j = 0; j < 2; ++j)
                acc[i][j] = __builtin_amdgcn_mfma_f32_16x16x32_bf16(af[i], bf[j], acc[i][j], 0, 0, 0);
    }
}

__global__ __launch_bounds__(256)
void gemm_k(const float* __restrict__ a0, int as0,
            const float* __restrict__ a1p, int as1,
            const float* __restrict__ a2p, int as2,
            const float* __restrict__ W, int K,
            const int* __restrict__ gate, int ksel,
            float* __restrict__ outp, int ostr)
{
    __shared__ alignas(16) u16 lsA[2][BMf * LDK];
    __shared__ alignas(16) u16 lsB[2][BNf * LDK];

    const int tid  = threadIdx.x;
    const int lane = tid & 63;
    const int wv   = tid >> 6;
    const int wm   = wv >> 1, wn = wv & 1;
    const int m0   = blockIdx.x * BMf;
    const int n0   = blockIdx.y * BNf;
    const int lr = tid >> 4;
    const int lc = (tid & 15) * 4;

    f32x4 acc[4][2];
#pragma unroll
    for (int i = 0; i < 4; ++i)
#pragma unroll
        for (int j = 0; j < 2; ++j) acc[i][j] = (f32x4){0.f, 0.f, 0.f, 0.f};

    const float* segp[3] = { a0, a1p, a2p };
    const int    segs[3] = { as0, as1, as2 };

    const int nkt = K / 64;
    RegTile S0, S1;
    load_tile(S0, segp, segs, W, K, 0, m0, n0, lr, lc);
    load_tile(S1, segp, segs, W, K, 1, m0, n0, lr, lc);
    stage_tile(S0, lsA[0], lsB[0], lr, lc);
    __syncthreads();

    for (int kt = 0; kt < nkt; kt += 2) {
        if (kt + 2 < nkt) load_tile(S0, segp, segs, W, K, kt + 2, m0, n0, lr, lc);
        do_mfma_f(lsA[0], lsB[0], wm, wn, lane, acc);
        stage_tile(S1, lsA[1], lsB[1], lr, lc);
        __syncthreads();
        if (kt + 3 < nkt) load_tile(S1, segp, segs, W, K, kt + 3, m0, n0, lr, lc);
        do_mfma_f(lsA[1], lsB[1], wm, wn, lane, acc);
        if (kt + 2 < nkt) {
            stage_tile(S0, lsA[0], lsB[0], lr, lc);
            __syncthreads();
        }
    }

    const int quad = lane >> 4;
    const int lcol = lane & 15;
#pragma unroll
    for (int i = 0; i < 4; ++i) {
#pragma unroll
        for (int r = 0; r < 4; ++r) {
            const int grow = m0 + wm * 64 + i * 16 + quad * 4 + r;
            if (gate[grow] == ksel) {
#pragma unroll
                for (int j = 0; j < 2; ++j) {
                    const int gcol = n0 + wn * 32 + j * 16 + lcol;
                    outp[(size_t)grow * ostr + gcol] = acc[i][j][r];
                }
            }
        }
    }
}

// ---------- prep_u + decide (fallback path only) ----------
__global__ __launch_bounds__(256)
void prep_u(const float* __restrict__ w_b11, const float* __restrict__ w_att,
            float* __restrict__ u)
{
    const int k  = (blockIdx.x & 7) * 256 + threadIdx.x;
    const int c0 = (blockIdx.x >> 3) * 16;
    float s0 = 0.f, s3 = 0.f;
    for (int c = c0; c < c0 + 16; ++c) {
        const float w = w_b11[(size_t)c * 2048 + k];
        s0 += w * w_att[7168 + c];
        s3 += w * w_att[3 * 8192 + 7168 + c];
    }
    atomicAdd(&u[k], s0);
    atomicAdd(&u[2048 + k], s3);
}

__global__ __launch_bounds__(256)
void decide(const float* __restrict__ X,
            const float* __restrict__ prev_a, const float* __restrict__ prev_b,
            const int* __restrict__ pdin,
            const float* __restrict__ w_att,
            const float* __restrict__ u,
            int* __restrict__ kbuf,
            float* __restrict__ out)
{
    const int lane = threadIdx.x & 63;
    const int wv   = threadIdx.x >> 6;
    const int b    = blockIdx.x * 4 + wv;
    const int pd   = pdin[b];

    const float* a1 = prev_a + (size_t)b * 2048 + 1024;
    const float* b1 = prev_b + (size_t)b * 2048 + 1024;
    const float* xr = X + (size_t)b * 1024;

    int k;
    float fv;
    if (pd == 0) {
        k = 2; fv = 1.f;
    } else {
        float d0 = 0.f, d3 = 0.f;
        const float* w0 = w_att;
        const float* w3 = w_att + 3 * 8192;
        const float* u0 = u;
        const float* u3 = u + 2048;
#pragma unroll
        for (int uu = 0; uu < 2; ++uu) {
            const int c = lane * 16 + uu * 8;
#pragma unroll
            for (int q = 0; q < 2; ++q) {
                const int cc = c + q * 4;
                float4 av = *(const float4*)&a1[cc];
                float4 bv = *(const float4*)&b1[cc];
                float4 xv = *(const float4*)&xr[cc];
                float4 wa0 = *(const float4*)&w0[2048 + cc];
                float4 wb0 = *(const float4*)&w0[3072 + cc];
                float4 wc0 = *(const float4*)&w0[6144 + cc];
                float4 wa3 = *(const float4*)&w3[2048 + cc];
                float4 wb3 = *(const float4*)&w3[3072 + cc];
                float4 wc3 = *(const float4*)&w3[6144 + cc];
                float4 ux0 = *(const float4*)&u0[cc];
                float4 ux3 = *(const float4*)&u3[cc];
                float4 ub0 = *(const float4*)&u0[1024 + cc];
                float4 ub3 = *(const float4*)&u3[1024 + cc];
                d0 += av.x*(wa0.x+wc0.x) + av.y*(wa0.y+wc0.y) + av.z*(wa0.z+wc0.z) + av.w*(wa0.w+wc0.w);
                d3 += av.x*(wa3.x+wc3.x) + av.y*(wa3.y+wc3.y) + av.z*(wa3.z+wc3.z) + av.w*(wa3.w+wc3.w);
                d0 += bv.x*wb0.x + bv.y*wb0.y + bv.z*wb0.z + bv.w*wb0.w;
                d3 += bv.x*wb3.x + bv.y*wb3.y + bv.z*wb3.z + bv.w*wb3.w;
                d0 += xv.x*ux0.x + xv.y*ux0.y + xv.z*ux0.z + xv.w*ux0.w;
                d3 += xv.x*ux3.x + xv.y*ux3.y + xv.z*ux3.z + xv.w*ux3.w;
                d0 += bv.x*ub0.x + bv.y*ub0.y + bv.z*ub0.z + bv.w*ub0.w;
                d3 += bv.x*ub3.x + bv.y*ub3.y + bv.z*ub3.z + bv.w*ub3.w;
            }
        }
#pragma unroll
        for (int off = 32; off; off >>= 1) {
            d0 += __shfl_xor(d0, off, 64);
            d3 += __shfl_xor(d3, off, 64);
        }
        k = (d3 > d0) ? 3 : 0;
        fv = (k == 3) ? 1.f : 0.f;
    }
    const float jv = (pd == 0) ? 0.f : fv;
    const int nd = (k == 2) ? pd + 1 : pd;

    float* outA = out;
    float* outB = out + OUT_B_OFF;

    const float4 z4 = make_float4(0.f, 0.f, 0.f, 0.f);
#pragma unroll
    for (int uu = 0; uu < 4; ++uu) {
        const int c = uu * 256 + lane * 4;
        *(float4*)&outA[(size_t)b * 2048 + c] = z4;
        *(float4*)&outB[(size_t)b * 2048 + c] = z4;
    }
    if (k == 3) {
#pragma unroll
        for (int uu = 0; uu < 4; ++uu) {
            const int c = uu * 256 + lane * 4;
            *(float4*)&outA[(size_t)b * 2048 + 1024 + c] = *(const float4*)&a1[c];
        }
    }
    if (lane == 0) {
        kbuf[b] = k;
        out[OUT_D_OFF + b] = (float)nd;
        out[OUT_F_OFF + b] = fv;
        out[OUT_J_OFF + b] = jv;
    }
}

// ---------- launch ----------
extern "C" void kernel_launch(void* const* d_in, const int* in_sizes, int n_in,
                              void* d_out, int out_size, void* d_ws, size_t ws_size,
                              hipStream_t stream)
{
    const float* X      = (const float*)d_in[0];
    const float* prev_a = (const float*)d_in[3];
    const float* prev_b = (const float*)d_in[4];
    const int*   pd     = (const int*)d_in[5];
    const float* w_a00  = (const float*)d_in[6];
    const float* w_a10  = (const float*)d_in[7];
    const float* w_b00  = (const float*)d_in[8];
    const float* w_b11  = (const float*)d_in[9];
    const float* w_b10  = (const float*)d_in[10];
    const float* w_att  = (const float*)d_in[12];

    float* u     = (float*)d_ws;                        // 16 KB
    float* wsum  = (float*)((char*)d_ws + WSUM_OFF);    // 8 KB
    int*   kbuf  = (int*)((char*)d_ws + KBUF_OFF);      // 16 KB
    int*   cnt   = (int*)((char*)d_ws + CNT_OFF);       // 16 B
    int*   lists = (int*)((char*)d_ws + LISTS_OFF);     // 48 KB
    u16*   ws16  = (u16*)((char*)d_ws + BF16_OFF);

    const float* a1 = prev_a + 1024;
    const float* b0 = prev_b;
    const float* b1 = prev_b + 1024;

    float* out   = (float*)d_out;
    float* outA1 = out + 1024;
    float* outB1 = out + OUT_B_OFF + 1024;

    dim3 blk(256);
    const bool fast = (ws_size >= WS_NEED);

    if (fast) {
        // memset covers u [0,16K) + cnt [40960,+16) (wsum/kbuf overwritten
        // before any read; lists bounded by cnt)
        hipMemsetAsync(d_ws, 0, CNT_OFF + 64, stream);
        prep<<<dim3(513), blk, 0, stream>>>(w_b11, w_att, u, wsum);
        decide_f<<<dim3(17408), blk, 0, stream>>>(X, prev_a, prev_b, pd,
            w_att, u, wsum, kbuf, lists, cnt, ws16, out,
            w_a00, w_a10, w_b00, w_b11, w_b10);

        int* l0 = lists;            // k==0 rows
        int* l2 = lists + 4096;     // k==2 rows
        int* l3 = lists + 8192;     // k==3 rows

        // Launch A (5 z): G1 (na00, k0), G2 (na10, k2),
        //   G4a (nb00 prefix [X,a1] -> fp32 partial in outB1),
        //   G3 (nb11, k3), G5a (nb10 prefix [X] -> partial in outB1).
        GPack p1;
        p1.d[0] = { XB, B0B, A1B, WA00B, NA00B,    3072, 3072, l0, &cnt[0], outA1, nullptr };
        p1.d[1] = { XB, B0B, 0u,  WA10B, NA10B,    2048, 2048, l2, &cnt[1], outA1, nullptr };
        p1.d[2] = { XB, A1B, 0u,  WB00B, NO_BCOPY, 2048, 3072, l0, &cnt[0], outB1, nullptr };
        p1.d[3] = { XB, B1B, 0u,  WB11B, NO_BCOPY, 2048, 2048, l3, &cnt[2], outB1, nullptr };
        p1.d[4] = { XB, 0u,  0u,  WB10B, NO_BCOPY, 1024, 2048, l2, &cnt[1], outB1, nullptr };
        gemm_gather<<<dim3(64, 16, 5), blk, 0, stream>>>(ws16, p1);

        // Launch B (2 z): G4b (nb00 suffix over na00, acc-init from partial),
        //   G5b (nb10 suffix over na10).  Exact fp32 accum order preserved.
        GPack p2;
        p2.d[0] = { NA00B, 0u, 0u, WB00B + 2048u, NO_BCOPY, 1024, 3072, l0, &cnt[0], outB1, outB1 };
        p2.d[1] = { NA10B, 0u, 0u, WB10B + 1024u, NO_BCOPY, 1024, 2048, l2, &cnt[1], outB1, outB1 };
        p2.d[2] = p2.d[0];   // unused (gridDim.z == 2)
        p2.d[3] = p2.d[0];
        p2.d[4] = p2.d[0];
        gemm_gather<<<dim3(64, 16, 2), blk, 0, stream>>>(ws16, p2);
    } else {
        // ---- fallback: proven round-6 fp32-staging path ----
        hipMemsetAsync(u, 0, 16384, stream);
        prep_u<<<dim3(512), blk, 0, stream>>>(w_b11, w_att, u);
        decide<<<dim3(Brows / 4), blk, 0, stream>>>(X, prev_a, prev_b, pd, w_att, u,
                                                    kbuf, out);
        dim3 grid(Brows / BMf, Hdim / BNf);
        gemm_k<<<grid, blk, 0, stream>>>(X, 1024, b0, 2048, a1, 2048,
                                         w_a00, 3072, kbuf, 0, outA1, 2048);
        gemm_k<<<grid, blk, 0, stream>>>(X, 1024, b0, 2048, nullptr, 0,
                                         w_a10, 2048, kbuf, 2, outA1, 2048);
        gemm_k<<<grid, blk, 0, stream>>>(X, 1024, b1, 2048, nullptr, 0,
                                         w_b11, 2048, pd, 1, outB1, 2048);
        gemm_k<<<grid, blk, 0, stream>>>(X, 1024, a1, 2048, outA1, 2048,
                                         w_b00, 3072, kbuf, 0, outB1, 2048);
        gemm_k<<<grid, blk, 0, stream>>>(X, 1024, outA1, 2048, nullptr, 0,
                                         w_b10, 2048, kbuf, 2, outB1, 2048);
    }
}